// Round 1
// baseline (588.783 us; speedup 1.0000x reference)
//
#include <hip/hip_runtime.h>
#include <hip/hip_bf16.h>

#define BB 4
#define SS 2048
#define EE 1024
#define HH 16
#define DD 64
#define MM (BB*SS)     // 8192
#define HD (HH*DD)     // 1024
#define NQKV (3*HD)    // 3072

typedef __bf16 bf16_t;
typedef __bf16 bf16x8 __attribute__((ext_vector_type(8)));
typedef float f32x4 __attribute__((ext_vector_type(4)));

#define MFMA16(a,b,c) __builtin_amdgcn_mfma_f32_16x16x32_bf16(a,b,c,0,0,0)
#define NEG_INF (-__builtin_huge_valf())

__device__ __forceinline__ void gload_lds16(const void* g, void* l) {
  __builtin_amdgcn_global_load_lds((const __attribute__((address_space(1))) unsigned int*)g,
                                   (__attribute__((address_space(3))) unsigned int*)l,
                                   16, 0, 0);
}

// ---------- f32 -> bf16, 8 elems/thread ----------
__global__ __launch_bounds__(256)
void k_f32_to_bf16(const float* __restrict__ in, bf16_t* __restrict__ out, int n8) {
  int i = blockIdx.x*256 + threadIdx.x;
  if (i >= n8) return;
  const float4* p = reinterpret_cast<const float4*>(in) + (size_t)i*2;
  float4 a = p[0], b = p[1];
  bf16x8 o;
  o[0]=(bf16_t)a.x; o[1]=(bf16_t)a.y; o[2]=(bf16_t)a.z; o[3]=(bf16_t)a.w;
  o[4]=(bf16_t)b.x; o[5]=(bf16_t)b.y; o[6]=(bf16_t)b.z; o[7]=(bf16_t)b.w;
  *reinterpret_cast<bf16x8*>(out + (size_t)i*8) = o;
}

// ---------- Wq/Wk/Wv [H,E,D] f32 -> Wt [3*H*D, E] bf16 (B^T layout) ----------
__global__ __launch_bounds__(256)
void k_conv_wqkv(const float* __restrict__ Wq, const float* __restrict__ Wk,
                 const float* __restrict__ Wv, bf16_t* __restrict__ Wt) {
  __shared__ float t[64][65];
  int wh = blockIdx.x;             // which*16 + h
  int which = wh >> 4, h = wh & 15;
  int e0 = blockIdx.y * 64;
  const float* W = (which==0) ? Wq : (which==1) ? Wk : Wv;
  const float* src = W + (size_t)h*EE*DD;
  int r = threadIdx.x >> 6, c = threadIdx.x & 63;
  #pragma unroll
  for (int i = 0; i < 16; ++i) {
    int e = i*4 + r;
    t[e][c] = src[(size_t)(e0+e)*DD + c];
  }
  __syncthreads();
  bf16_t* dst = Wt + (size_t)(which*HD + h*DD)*EE;
  #pragma unroll
  for (int i = 0; i < 16; ++i) {
    int d = i*4 + r;
    dst[(size_t)d*EE + e0 + c] = (bf16_t)t[c][d];
  }
}

// ---------- GEMM: C[M,N] = A[M,K] * Bt[N,K]^T  (bf16 in, f32 acc) ----------
// EPI==0: scatter to Q,K [B,H,S,D] bf16 and V^T [B,H,D,S] bf16 (N=3072)
// EPI==1: f32 out = acc + bias (N=1024)
template<int EPI>
__global__ __launch_bounds__(256)
void k_gemm(const bf16_t* __restrict__ A, const bf16_t* __restrict__ Bt,
            bf16_t* __restrict__ Qp, bf16_t* __restrict__ Kp, bf16_t* __restrict__ Vtp,
            const float* __restrict__ bias, float* __restrict__ Cout, int Kdim) {
  __shared__ __align__(16) bf16_t As[128*32];
  __shared__ __align__(16) bf16_t Bs[128*32];
  int m0 = blockIdx.y * 128, n0 = blockIdx.x * 128;
  int tid = threadIdx.x;
  int lane = tid & 63, w = tid >> 6;
  int wr = w >> 1, wc = w & 1;
  int lr = lane & 15, lg = lane >> 4;

  f32x4 acc[4][4];
  #pragma unroll
  for (int i=0;i<4;i++)
    #pragma unroll
    for (int j=0;j<4;j++) acc[i][j] = (f32x4){0.f,0.f,0.f,0.f};

  const int nk = Kdim >> 5;
  int srow = tid >> 2;            // 0..63
  int scol = (tid & 3) << 3;      // 0,8,16,24

#define STAGE_TILE(kt) do { \
    const bf16_t* Ab_ = A  + (size_t)m0*Kdim + ((kt)<<5); \
    const bf16_t* Bb_ = Bt + (size_t)n0*Kdim + ((kt)<<5); \
    _Pragma("unroll") \
    for (int j_ = 0; j_ < 2; ++j_) { \
      int row_ = j_*64 + srow; \
      unsigned off_ = (unsigned)(j_*4096 + w*1024); \
      gload_lds16(Ab_ + (size_t)row_*Kdim + scol, (char*)As + off_); \
      gload_lds16(Bb_ + (size_t)row_*Kdim + scol, (char*)Bs + off_); \
    } \
  } while(0)

  STAGE_TILE(0);
  for (int kt = 0; kt < nk; ++kt) {
    __syncthreads();   // drains vmcnt(0): staged data visible
    bf16x8 af[4], bf[4];
    #pragma unroll
    for (int i=0;i<4;i++) {
      af[i] = *reinterpret_cast<const bf16x8*>(As + ((wr*64 + i*16 + lr)<<5) + (lg<<3));
      bf[i] = *reinterpret_cast<const bf16x8*>(Bs + ((wc*64 + i*16 + lr)<<5) + (lg<<3));
    }
    #pragma unroll
    for (int i=0;i<4;i++)
      #pragma unroll
      for (int j=0;j<4;j++)
        acc[i][j] = MFMA16(af[i], bf[j], acc[i][j]);
    __syncthreads();   // all waves done reading before restage
    if (kt+1 < nk) STAGE_TILE(kt+1);
  }
#undef STAGE_TILE

  if (EPI == 0) {
    int which = n0 >> 10;   // uniform per block (n-tile never crosses a 1024 boundary)
    #pragma unroll
    for (int i=0;i<4;i++) {
      #pragma unroll
      for (int j=0;j<4;j++) {
        int n = n0 + wc*64 + j*16 + lr;
        int hd = n & 1023, h = hd >> 6, d = hd & 63;
        #pragma unroll
        for (int r=0;r<4;r++) {
          int m = m0 + wr*64 + i*16 + lg*4 + r;
          int b = m >> 11, s = m & 2047;
          size_t bh = (size_t)(b*HH + h);
          bf16_t val = (bf16_t)acc[i][j][r];
          if (which == 0)      Qp [(bh*SS + s)*DD + d] = val;
          else if (which == 1) Kp [(bh*SS + s)*DD + d] = val;
          else                 Vtp[(bh*DD + d)*SS + s] = val;
        }
      }
    }
  } else {
    float bv[4];
    #pragma unroll
    for (int j=0;j<4;j++) bv[j] = bias[n0 + wc*64 + j*16 + lr];
    #pragma unroll
    for (int i=0;i<4;i++)
      #pragma unroll
      for (int j=0;j<4;j++) {
        int n = n0 + wc*64 + j*16 + lr;
        #pragma unroll
        for (int r=0;r<4;r++) {
          int m = m0 + wr*64 + i*16 + lg*4 + r;
          Cout[(size_t)m*HD + n] = acc[i][j][r] + bv[j];
        }
      }
  }
}

// ---------- flash attention (causal): 1 block = (b,h, 64 q-rows), 4 waves x 16 rows ----------
__global__ __launch_bounds__(256)
void k_attn(const bf16_t* __restrict__ Q, const bf16_t* __restrict__ K,
            const bf16_t* __restrict__ Vt, bf16_t* __restrict__ AO) {
  __shared__ __align__(16) bf16_t P[4][16][72];   // per-wave, row stride 144B (2-way bank alias = free)
  int blk = blockIdx.x;
  int bh = blk >> 5, qt = blk & 31;
  int tid = threadIdx.x, lane = tid & 63, w = tid >> 6;
  int lr = lane & 15, lg = lane >> 4;
  const bf16_t* Qb = Q  + (size_t)bh * SS * DD;
  const bf16_t* Kp = K  + (size_t)bh * SS * DD;
  const bf16_t* Vp = Vt + (size_t)bh * DD * SS;
  int qrow0 = qt*64 + w*16;

  bf16x8 qf[2];
  #pragma unroll
  for (int kk=0;kk<2;kk++)
    qf[kk] = *reinterpret_cast<const bf16x8*>(Qb + (size_t)(qrow0 + lr)*DD + kk*32 + lg*8);

  f32x4 po[4];
  #pragma unroll
  for (int i=0;i<4;i++) po[i] = (f32x4){0.f,0.f,0.f,0.f};
  float mrow[4] = {NEG_INF, NEG_INF, NEG_INF, NEG_INF};
  float lrow[4] = {0.f,0.f,0.f,0.f};
  const float scale = 0.125f;   // 1/sqrt(64)

  for (int t = 0; t <= qt; ++t) {
    int kv0 = t*64;
    // ---- S = (Q K^T) * scale ----
    f32x4 sa[4];
    #pragma unroll
    for (int ct=0; ct<4; ++ct) {
      const bf16_t* kr = Kp + (size_t)(kv0 + ct*16 + lr)*DD + lg*8;
      bf16x8 k0 = *reinterpret_cast<const bf16x8*>(kr);
      bf16x8 k1 = *reinterpret_cast<const bf16x8*>(kr + 32);
      f32x4 c = (f32x4){0.f,0.f,0.f,0.f};
      c = MFMA16(qf[0], k0, c);
      c = MFMA16(qf[1], k1, c);
      sa[ct] = c;
    }
    #pragma unroll
    for (int ct=0;ct<4;ct++)
      #pragma unroll
      for (int r=0;r<4;r++) sa[ct][r] *= scale;
    if (t == qt) {   // causal mask only on the diagonal tile
      #pragma unroll
      for (int ct=0;ct<4;ct++) {
        int col = kv0 + ct*16 + lr;
        #pragma unroll
        for (int r=0;r<4;r++) {
          int row = qrow0 + lg*4 + r;
          if (col > row) sa[ct][r] = NEG_INF;
        }
      }
    }
    // ---- online softmax (rows live in 16-lane groups) ----
    float fscale[4];
    #pragma unroll
    for (int r=0;r<4;r++) {
      float v = fmaxf(fmaxf(sa[0][r], sa[1][r]), fmaxf(sa[2][r], sa[3][r]));
      v = fmaxf(v, __shfl_xor(v, 1));
      v = fmaxf(v, __shfl_xor(v, 2));
      v = fmaxf(v, __shfl_xor(v, 4));
      v = fmaxf(v, __shfl_xor(v, 8));
      float mn = fmaxf(mrow[r], v);
      fscale[r] = __expf(mrow[r] - mn);
      mrow[r] = mn;
    }
    float rs[4] = {0.f,0.f,0.f,0.f};
    #pragma unroll
    for (int ct=0;ct<4;ct++)
      #pragma unroll
      for (int r=0;r<4;r++) {
        float p = __expf(sa[ct][r] - mrow[r]);
        sa[ct][r] = p;
        rs[r] += p;
      }
    #pragma unroll
    for (int r=0;r<4;r++) {
      float v = rs[r];
      v += __shfl_xor(v, 1);
      v += __shfl_xor(v, 2);
      v += __shfl_xor(v, 4);
      v += __shfl_xor(v, 8);
      lrow[r] = lrow[r]*fscale[r] + v;
    }
    #pragma unroll
    for (int i=0;i<4;i++)
      #pragma unroll
      for (int r=0;r<4;r++) po[i][r] *= fscale[r];
    // ---- P (C-layout) -> LDS -> A-operand layout ----
    #pragma unroll
    for (int ct=0;ct<4;ct++)
      #pragma unroll
      for (int r=0;r<4;r++)
        P[w][lg*4+r][ct*16+lr] = (bf16_t)sa[ct][r];
    // ---- O += P V  (V^T rows are contiguous kv) ----
    #pragma unroll
    for (int kk=0;kk<2;kk++) {
      bf16x8 pf = *reinterpret_cast<const bf16x8*>(&P[w][lr][kk*32 + lg*8]);
      #pragma unroll
      for (int ctd=0;ctd<4;ctd++) {
        bf16x8 vf = *reinterpret_cast<const bf16x8*>(Vp + (size_t)(ctd*16 + lr)*SS + kv0 + kk*32 + lg*8);
        po[ctd] = MFMA16(pf, vf, po[ctd]);
      }
    }
  }
  // ---- epilogue: O /= l, write concat-head layout [B*S, H*D] bf16 ----
  int b = bh >> 4, h = bh & 15;
  #pragma unroll
  for (int r=0;r<4;r++) {
    float inv = 1.0f / lrow[r];
    int m = b*SS + qrow0 + lg*4 + r;
    bf16_t* dst = AO + (size_t)m*HD + h*DD;
    #pragma unroll
    for (int ctd=0;ctd<4;ctd++) dst[ctd*16 + lr] = (bf16_t)(po[ctd][r] * inv);
  }
}

extern "C" void kernel_launch(void* const* d_in, const int* in_sizes, int n_in,
                              void* d_out, int out_size, void* d_ws, size_t ws_size,
                              hipStream_t stream) {
  const float* x  = (const float*)d_in[0];
  const float* Wq = (const float*)d_in[1];
  const float* Wk = (const float*)d_in[2];
  const float* Wv = (const float*)d_in[3];
  const float* Wo = (const float*)d_in[4];
  const float* bo = (const float*)d_in[5];
  float* out = (float*)d_out;

  char* ws = (char*)d_ws;
  bf16_t* xb  = (bf16_t*)(ws + 0);          // [8192,1024]        16 MB
  bf16_t* wt  = (bf16_t*)(ws + 16777216);   // [3072,1024]         6 MB
  bf16_t* wob = (bf16_t*)(ws + 23068672);   // [1024,1024]         2 MB
  bf16_t* Qb  = (bf16_t*)(ws + 25165824);   // [B,H,S,D]          16 MB
  bf16_t* Kb  = (bf16_t*)(ws + 41943040);   // [B,H,S,D]          16 MB
  bf16_t* Vtb = (bf16_t*)(ws + 58720256);   // [B,H,D,S]          16 MB
  bf16_t* AO  = (bf16_t*)(ws + 75497472);   // [8192,1024]        16 MB
                                            // total 92,274,688 B

  k_f32_to_bf16<<<(MM*EE/8)/256, 256, 0, stream>>>(x,  xb,  MM*EE/8);
  k_f32_to_bf16<<<(EE*EE/8)/256, 256, 0, stream>>>(Wo, wob, EE*EE/8);
  dim3 gw(48, 16);
  k_conv_wqkv<<<gw, 256, 0, stream>>>(Wq, Wk, Wv, wt);

  dim3 g1(NQKV/128, MM/128);    // (24, 64)
  k_gemm<0><<<g1, 256, 0, stream>>>(xb, wt, Qb, Kb, Vtb, nullptr, nullptr, EE);

  k_attn<<<BB*HH*(SS/64), 256, 0, stream>>>(Qb, Kb, Vtb, AO);

  dim3 g3(HD/128, MM/128);      // (8, 64)
  k_gemm<1><<<g3, 256, 0, stream>>>(AO, wob, nullptr, nullptr, nullptr, bo, out, HD);
}

// Round 2
// 247.883 us; speedup vs baseline: 2.3752x; 2.3752x over previous
//
#include <hip/hip_runtime.h>
#include <hip/hip_bf16.h>

#define BB 4
#define SS 2048
#define EE 1024
#define HH 16
#define DD 64
#define MM (BB*SS)     // 8192
#define HD (HH*DD)     // 1024
#define NQKV (3*HD)    // 3072

typedef __bf16 bf16_t;
typedef __bf16 bf16x8 __attribute__((ext_vector_type(8)));
typedef float f32x4 __attribute__((ext_vector_type(4)));

#define MFMA16(a,b,c) __builtin_amdgcn_mfma_f32_16x16x32_bf16(a,b,c,0,0,0)
#define NEG_INF (-__builtin_huge_valf())

__device__ __forceinline__ void gload_lds16(const void* g, void* l) {
  __builtin_amdgcn_global_load_lds((const __attribute__((address_space(1))) unsigned int*)g,
                                   (__attribute__((address_space(3))) unsigned int*)l,
                                   16, 0, 0);
}

// ---------- f32 -> bf16, 8 elems/thread ----------
__global__ __launch_bounds__(256)
void k_f32_to_bf16(const float* __restrict__ in, bf16_t* __restrict__ out, int n8) {
  int i = blockIdx.x*256 + threadIdx.x;
  if (i >= n8) return;
  const float4* p = reinterpret_cast<const float4*>(in) + (size_t)i*2;
  float4 a = p[0], b = p[1];
  bf16x8 o;
  o[0]=(bf16_t)a.x; o[1]=(bf16_t)a.y; o[2]=(bf16_t)a.z; o[3]=(bf16_t)a.w;
  o[4]=(bf16_t)b.x; o[5]=(bf16_t)b.y; o[6]=(bf16_t)b.z; o[7]=(bf16_t)b.w;
  *reinterpret_cast<bf16x8*>(out + (size_t)i*8) = o;
}

// ---------- Wq/Wk/Wv [H,E,D] f32 -> Wt [3*H*D, E] bf16 (B^T layout) ----------
__global__ __launch_bounds__(256)
void k_conv_wqkv(const float* __restrict__ Wq, const float* __restrict__ Wk,
                 const float* __restrict__ Wv, bf16_t* __restrict__ Wt) {
  __shared__ float t[64][65];
  int wh = blockIdx.x;             // which*16 + h
  int which = wh >> 4, h = wh & 15;
  int e0 = blockIdx.y * 64;
  const float* W = (which==0) ? Wq : (which==1) ? Wk : Wv;
  const float* src = W + (size_t)h*EE*DD;
  int r = threadIdx.x >> 6, c = threadIdx.x & 63;
  #pragma unroll
  for (int i = 0; i < 16; ++i) {
    int e = i*4 + r;
    t[e][c] = src[(size_t)(e0+e)*DD + c];
  }
  __syncthreads();
  bf16_t* dst = Wt + (size_t)(which*HD + h*DD)*EE;
  #pragma unroll
  for (int i = 0; i < 16; ++i) {
    int d = i*4 + r;
    dst[(size_t)d*EE + e0 + c] = (bf16_t)t[c][d];
  }
}

// ---------- GEMM: C[M,N] = A[M,K] * Bt[N,K]^T  (bf16 in, f32 acc) ----------
template<int EPI>
__global__ __launch_bounds__(256)
void k_gemm(const bf16_t* __restrict__ A, const bf16_t* __restrict__ Bt,
            bf16_t* __restrict__ Qp, bf16_t* __restrict__ Kp, bf16_t* __restrict__ Vtp,
            const float* __restrict__ bias, float* __restrict__ Cout, int Kdim) {
  __shared__ __align__(16) bf16_t As[128*32];
  __shared__ __align__(16) bf16_t Bs[128*32];
  int m0 = blockIdx.y * 128, n0 = blockIdx.x * 128;
  int tid = threadIdx.x;
  int lane = tid & 63, w = tid >> 6;
  int wr = w >> 1, wc = w & 1;
  int lr = lane & 15, lg = lane >> 4;

  f32x4 acc[4][4];
  #pragma unroll
  for (int i=0;i<4;i++)
    #pragma unroll
    for (int j=0;j<4;j++) acc[i][j] = (f32x4){0.f,0.f,0.f,0.f};

  const int nk = Kdim >> 5;
  int srow = tid >> 2;            // 0..63
  int scol = (tid & 3) << 3;      // 0,8,16,24

#define STAGE_TILE(kt) do { \
    const bf16_t* Ab_ = A  + (size_t)m0*Kdim + ((kt)<<5); \
    const bf16_t* Bb_ = Bt + (size_t)n0*Kdim + ((kt)<<5); \
    _Pragma("unroll") \
    for (int j_ = 0; j_ < 2; ++j_) { \
      int row_ = j_*64 + srow; \
      unsigned off_ = (unsigned)(j_*4096 + w*1024); \
      gload_lds16(Ab_ + (size_t)row_*Kdim + scol, (char*)As + off_); \
      gload_lds16(Bb_ + (size_t)row_*Kdim + scol, (char*)Bs + off_); \
    } \
  } while(0)

  STAGE_TILE(0);
  for (int kt = 0; kt < nk; ++kt) {
    __syncthreads();
    bf16x8 af[4], bf[4];
    #pragma unroll
    for (int i=0;i<4;i++) {
      af[i] = *reinterpret_cast<const bf16x8*>(As + ((wr*64 + i*16 + lr)<<5) + (lg<<3));
      bf[i] = *reinterpret_cast<const bf16x8*>(Bs + ((wc*64 + i*16 + lr)<<5) + (lg<<3));
    }
    #pragma unroll
    for (int i=0;i<4;i++)
      #pragma unroll
      for (int j=0;j<4;j++)
        acc[i][j] = MFMA16(af[i], bf[j], acc[i][j]);
    __syncthreads();
    if (kt+1 < nk) STAGE_TILE(kt+1);
  }
#undef STAGE_TILE

  if (EPI == 0) {
    int which = n0 >> 10;
    #pragma unroll
    for (int i=0;i<4;i++) {
      #pragma unroll
      for (int j=0;j<4;j++) {
        int n = n0 + wc*64 + j*16 + lr;
        int hd = n & 1023, h = hd >> 6, d = hd & 63;
        #pragma unroll
        for (int r=0;r<4;r++) {
          int m = m0 + wr*64 + i*16 + lg*4 + r;
          int b = m >> 11, s = m & 2047;
          size_t bh = (size_t)(b*HH + h);
          bf16_t val = (bf16_t)acc[i][j][r];
          if (which == 0)      Qp [(bh*SS + s)*DD + d] = val;
          else if (which == 1) Kp [(bh*SS + s)*DD + d] = val;
          else                 Vtp[(bh*DD + d)*SS + s] = val;
        }
      }
    }
  } else {
    float bv[4];
    #pragma unroll
    for (int j=0;j<4;j++) bv[j] = bias[n0 + wc*64 + j*16 + lr];
    #pragma unroll
    for (int i=0;i<4;i++)
      #pragma unroll
      for (int j=0;j<4;j++) {
        int n = n0 + wc*64 + j*16 + lr;
        #pragma unroll
        for (int r=0;r<4;r++) {
          int m = m0 + wr*64 + i*16 + lg*4 + r;
          Cout[(size_t)m*HD + n] = acc[i][j][r] + bv[j];
        }
      }
  }
}

// ---------- flash attention (causal), v2 ----------
// Block = 8 waves = 512 thr; handles TWO 128-row q-tiles (p = u and 15-u) so every
// block does exactly 34 kv64-iterations. K/V tiles staged in LDS (double-buffered,
// global_load_lds w16, chunk-XOR swizzle), shared by all 8 waves.
__global__ __launch_bounds__(512)
void k_attn(const bf16_t* __restrict__ Q, const bf16_t* __restrict__ K,
            const bf16_t* __restrict__ Vt, bf16_t* __restrict__ AO) {
  __shared__ __align__(16) bf16_t Ks[2][64*64];
  __shared__ __align__(16) bf16_t Vs[2][64*64];
  __shared__ __align__(16) bf16_t P[8][16][72];

  // XCD swizzle: all 8 pair-blocks of one bh on one XCD (bh K+V = 0.5MB; 8 bh = 4MB L2)
  int id = blockIdx.x;
  int m8 = id & 7, d8 = id >> 3;
  int bh = m8*8 + (d8 >> 3);
  int u  = d8 & 7;

  int tid = threadIdx.x, lane = tid & 63, w = tid >> 6;
  int lr = lane & 15, lg = lane >> 4;
  const bf16_t* Qb = Q  + (size_t)bh * SS * DD;
  const bf16_t* Kp = K  + (size_t)bh * SS * DD;
  const bf16_t* Vp = Vt + (size_t)bh * DD * SS;
  int b = bh >> 4, h = bh & 15;

  // staging geometry: thread tid owns LDS chunk tid (16B): row tid>>3, slot tid&7.
  // stored slot s holds global chunk s ^ (row&7)  (XOR involution; read does same XOR)
  int srow = tid >> 3;
  int gchunk = (tid & 7) ^ (srow & 7);
  const float scale = 0.125f;   // 1/sqrt(64)

#define STAGE_KV(t, buf) do { \
    int kv0_ = (t)*64; \
    gload_lds16(Kp + (size_t)(kv0_ + srow)*DD + gchunk*8, (char*)Ks[buf] + w*1024); \
    gload_lds16(Vp + (size_t)srow*SS + kv0_ + gchunk*8,   (char*)Vs[buf] + w*1024); \
  } while(0)

  for (int ph = 0; ph < 2; ++ph) {
    int p = ph ? (15 - u) : u;
    int nt = 2*p + 2;            // even -> last tile uses buf1, next phase's STAGE(0)->buf0 is safe
    int qrow0 = p*128 + w*16;

    bf16x8 qf[2];
    #pragma unroll
    for (int kk=0;kk<2;kk++)
      qf[kk] = *reinterpret_cast<const bf16x8*>(Qb + (size_t)(qrow0 + lr)*DD + kk*32 + lg*8);

    f32x4 po[4];
    #pragma unroll
    for (int i=0;i<4;i++) po[i] = (f32x4){0.f,0.f,0.f,0.f};
    float mrow[4] = {NEG_INF, NEG_INF, NEG_INF, NEG_INF};
    float lrow[4] = {0.f,0.f,0.f,0.f};

    STAGE_KV(0, 0);
    for (int t = 0; t < nt; ++t) {
      __syncthreads();                      // tile t staged & everyone done with buf t-2
      if (t+1 < nt) STAGE_KV(t+1, (t+1)&1);
      const bf16_t* Kb = Ks[t&1];
      const bf16_t* Vb = Vs[t&1];
      int kv0 = t*64;
      if (kv0 > qrow0 + 15) continue;       // fully masked for this wave (barrier already done)

      // ---- S = (Q K^T) * scale ----
      f32x4 sa[4];
      #pragma unroll
      for (int ct=0; ct<4; ++ct) {
        int rr = ct*16 + lr;
        int sw = rr & 7;
        bf16x8 k0 = *reinterpret_cast<const bf16x8*>(Kb + rr*64 + ((lg     ^ sw) << 3));
        bf16x8 k1 = *reinterpret_cast<const bf16x8*>(Kb + rr*64 + (((4+lg) ^ sw) << 3));
        f32x4 c = (f32x4){0.f,0.f,0.f,0.f};
        c = MFMA16(qf[0], k0, c);
        c = MFMA16(qf[1], k1, c);
        sa[ct] = c;
      }
      #pragma unroll
      for (int ct=0;ct<4;ct++)
        #pragma unroll
        for (int r=0;r<4;r++) sa[ct][r] *= scale;
      if (kv0 + 63 > qrow0) {               // tile crosses diagonal for this wave
        #pragma unroll
        for (int ct=0;ct<4;ct++) {
          int col = kv0 + ct*16 + lr;
          #pragma unroll
          for (int r=0;r<4;r++) {
            int row = qrow0 + lg*4 + r;
            if (col > row) sa[ct][r] = NEG_INF;
          }
        }
      }
      // ---- online softmax (rows in 16-lane groups) ----
      float fscale[4];
      #pragma unroll
      for (int r=0;r<4;r++) {
        float v = fmaxf(fmaxf(sa[0][r], sa[1][r]), fmaxf(sa[2][r], sa[3][r]));
        v = fmaxf(v, __shfl_xor(v, 1));
        v = fmaxf(v, __shfl_xor(v, 2));
        v = fmaxf(v, __shfl_xor(v, 4));
        v = fmaxf(v, __shfl_xor(v, 8));
        float mn = fmaxf(mrow[r], v);
        fscale[r] = __expf(mrow[r] - mn);
        mrow[r] = mn;
      }
      float rs[4] = {0.f,0.f,0.f,0.f};
      #pragma unroll
      for (int ct=0;ct<4;ct++)
        #pragma unroll
        for (int r=0;r<4;r++) {
          float pv = __expf(sa[ct][r] - mrow[r]);
          sa[ct][r] = pv;
          rs[r] += pv;
        }
      #pragma unroll
      for (int r=0;r<4;r++) {
        float v = rs[r];
        v += __shfl_xor(v, 1);
        v += __shfl_xor(v, 2);
        v += __shfl_xor(v, 4);
        v += __shfl_xor(v, 8);
        lrow[r] = lrow[r]*fscale[r] + v;
      }
      #pragma unroll
      for (int i=0;i<4;i++)
        #pragma unroll
        for (int r=0;r<4;r++) po[i][r] *= fscale[r];
      // ---- P (C-layout) -> per-wave LDS -> A-operand layout ----
      #pragma unroll
      for (int ct=0;ct<4;ct++)
        #pragma unroll
        for (int r=0;r<4;r++)
          P[w][lg*4+r][ct*16+lr] = (bf16_t)sa[ct][r];
      // ---- O += P V ----
      #pragma unroll
      for (int kk=0;kk<2;kk++) {
        bf16x8 pf = *reinterpret_cast<const bf16x8*>(&P[w][lr][kk*32 + lg*8]);
        #pragma unroll
        for (int ctd=0;ctd<4;ctd++) {
          int rr = ctd*16 + lr;
          bf16x8 vf = *reinterpret_cast<const bf16x8*>(Vb + rr*64 + (((kk*4+lg) ^ (rr&7)) << 3));
          po[ctd] = MFMA16(pf, vf, po[ctd]);
        }
      }
    }
    // ---- epilogue: O /= l, concat-head layout [B*S, H*D] bf16 ----
    #pragma unroll
    for (int r=0;r<4;r++) {
      float inv = 1.0f / lrow[r];
      int m = b*SS + qrow0 + lg*4 + r;
      bf16_t* dst = AO + (size_t)m*HD + h*DD;
      #pragma unroll
      for (int ctd=0;ctd<4;ctd++) dst[ctd*16 + lr] = (bf16_t)(po[ctd][r] * inv);
    }
  }
#undef STAGE_KV
}

extern "C" void kernel_launch(void* const* d_in, const int* in_sizes, int n_in,
                              void* d_out, int out_size, void* d_ws, size_t ws_size,
                              hipStream_t stream) {
  const float* x  = (const float*)d_in[0];
  const float* Wq = (const float*)d_in[1];
  const float* Wk = (const float*)d_in[2];
  const float* Wv = (const float*)d_in[3];
  const float* Wo = (const float*)d_in[4];
  const float* bo = (const float*)d_in[5];
  float* out = (float*)d_out;

  char* ws = (char*)d_ws;
  bf16_t* xb  = (bf16_t*)(ws + 0);          // [8192,1024]        16 MB
  bf16_t* wt  = (bf16_t*)(ws + 16777216);   // [3072,1024]         6 MB
  bf16_t* wob = (bf16_t*)(ws + 23068672);   // [1024,1024]         2 MB
  bf16_t* Qb  = (bf16_t*)(ws + 25165824);   // [B,H,S,D]          16 MB
  bf16_t* Kb  = (bf16_t*)(ws + 41943040);   // [B,H,S,D]          16 MB
  bf16_t* Vtb = (bf16_t*)(ws + 58720256);   // [B,H,D,S]          16 MB
  bf16_t* AO  = (bf16_t*)(ws + 75497472);   // [8192,1024]        16 MB

  k_f32_to_bf16<<<(MM*EE/8)/256, 256, 0, stream>>>(x,  xb,  MM*EE/8);
  k_f32_to_bf16<<<(EE*EE/8)/256, 256, 0, stream>>>(Wo, wob, EE*EE/8);
  dim3 gw(48, 16);
  k_conv_wqkv<<<gw, 256, 0, stream>>>(Wq, Wk, Wv, wt);

  dim3 g1(NQKV/128, MM/128);    // (24, 64)
  k_gemm<0><<<g1, 256, 0, stream>>>(xb, wt, Qb, Kb, Vtb, nullptr, nullptr, EE);

  k_attn<<<BB*HH*8, 512, 0, stream>>>(Qb, Kb, Vtb, AO);

  dim3 g3(HD/128, MM/128);      // (8, 64)
  k_gemm<1><<<g3, 256, 0, stream>>>(AO, wob, nullptr, nullptr, nullptr, bo, out, HD);
}

// Round 3
// 225.944 us; speedup vs baseline: 2.6059x; 1.0971x over previous
//
#include <hip/hip_runtime.h>
#include <hip/hip_bf16.h>

#define BB 4
#define SS 2048
#define EE 1024
#define HH 16
#define DD 64
#define MM (BB*SS)     // 8192
#define HD (HH*DD)     // 1024
#define NQKV (3*HD)    // 3072

typedef __bf16 bf16_t;
typedef __bf16 bf16x8 __attribute__((ext_vector_type(8)));
typedef float f32x4 __attribute__((ext_vector_type(4)));

#define MFMA16(a,b,c) __builtin_amdgcn_mfma_f32_16x16x32_bf16(a,b,c,0,0,0)
#define NEG_INF (-__builtin_huge_valf())
#define QSCALE 0.1803368801111204f   // (1/sqrt(64)) * log2(e): softmax runs in exp2 domain

__device__ __forceinline__ void gload_lds16(const void* g, void* l) {
  __builtin_amdgcn_global_load_lds((const __attribute__((address_space(1))) unsigned int*)g,
                                   (__attribute__((address_space(3))) unsigned int*)l,
                                   16, 0, 0);
}

// ---------- f32 -> bf16, 8 elems/thread ----------
__global__ __launch_bounds__(256)
void k_f32_to_bf16(const float* __restrict__ in, bf16_t* __restrict__ out, int n8) {
  int i = blockIdx.x*256 + threadIdx.x;
  if (i >= n8) return;
  const float4* p = reinterpret_cast<const float4*>(in) + (size_t)i*2;
  float4 a = p[0], b = p[1];
  bf16x8 o;
  o[0]=(bf16_t)a.x; o[1]=(bf16_t)a.y; o[2]=(bf16_t)a.z; o[3]=(bf16_t)a.w;
  o[4]=(bf16_t)b.x; o[5]=(bf16_t)b.y; o[6]=(bf16_t)b.z; o[7]=(bf16_t)b.w;
  *reinterpret_cast<bf16x8*>(out + (size_t)i*8) = o;
}

// ---------- Wq/Wk/Wv [H,E,D] f32 -> Wt [3*H*D, E] bf16 (B^T layout) ----------
__global__ __launch_bounds__(256)
void k_conv_wqkv(const float* __restrict__ Wq, const float* __restrict__ Wk,
                 const float* __restrict__ Wv, bf16_t* __restrict__ Wt) {
  __shared__ float t[64][65];
  int wh = blockIdx.x;             // which*16 + h
  int which = wh >> 4, h = wh & 15;
  int e0 = blockIdx.y * 64;
  const float* W = (which==0) ? Wq : (which==1) ? Wk : Wv;
  const float* src = W + (size_t)h*EE*DD;
  int r = threadIdx.x >> 6, c = threadIdx.x & 63;
  #pragma unroll
  for (int i = 0; i < 16; ++i) {
    int e = i*4 + r;
    t[e][c] = src[(size_t)(e0+e)*DD + c];
  }
  __syncthreads();
  bf16_t* dst = Wt + (size_t)(which*HD + h*DD)*EE;
  #pragma unroll
  for (int i = 0; i < 16; ++i) {
    int d = i*4 + r;
    dst[(size_t)d*EE + e0 + c] = (bf16_t)t[c][d];
  }
}

// ---------- GEMM: C[M,N] = A[M,K] * Bt[N,K]^T  (bf16 in, f32 acc) ----------
template<int EPI>
__global__ __launch_bounds__(256)
void k_gemm(const bf16_t* __restrict__ A, const bf16_t* __restrict__ Bt,
            bf16_t* __restrict__ Qp, bf16_t* __restrict__ Kp, bf16_t* __restrict__ Vtp,
            const float* __restrict__ bias, float* __restrict__ Cout, int Kdim) {
  __shared__ __align__(16) bf16_t As[128*32];
  __shared__ __align__(16) bf16_t Bs[128*32];
  int m0 = blockIdx.y * 128, n0 = blockIdx.x * 128;
  int tid = threadIdx.x;
  int lane = tid & 63, w = tid >> 6;
  int wr = w >> 1, wc = w & 1;
  int lr = lane & 15, lg = lane >> 4;

  f32x4 acc[4][4];
  #pragma unroll
  for (int i=0;i<4;i++)
    #pragma unroll
    for (int j=0;j<4;j++) acc[i][j] = (f32x4){0.f,0.f,0.f,0.f};

  const int nk = Kdim >> 5;
  int srow = tid >> 2;            // 0..63
  int scol = (tid & 3) << 3;      // 0,8,16,24

#define STAGE_TILE(kt) do { \
    const bf16_t* Ab_ = A  + (size_t)m0*Kdim + ((kt)<<5); \
    const bf16_t* Bb_ = Bt + (size_t)n0*Kdim + ((kt)<<5); \
    _Pragma("unroll") \
    for (int j_ = 0; j_ < 2; ++j_) { \
      int row_ = j_*64 + srow; \
      unsigned off_ = (unsigned)(j_*4096 + w*1024); \
      gload_lds16(Ab_ + (size_t)row_*Kdim + scol, (char*)As + off_); \
      gload_lds16(Bb_ + (size_t)row_*Kdim + scol, (char*)Bs + off_); \
    } \
  } while(0)

  STAGE_TILE(0);
  for (int kt = 0; kt < nk; ++kt) {
    __syncthreads();
    bf16x8 af[4], bf[4];
    #pragma unroll
    for (int i=0;i<4;i++) {
      af[i] = *reinterpret_cast<const bf16x8*>(As + ((wr*64 + i*16 + lr)<<5) + (lg<<3));
      bf[i] = *reinterpret_cast<const bf16x8*>(Bs + ((wc*64 + i*16 + lr)<<5) + (lg<<3));
    }
    #pragma unroll
    for (int i=0;i<4;i++)
      #pragma unroll
      for (int j=0;j<4;j++)
        acc[i][j] = MFMA16(af[i], bf[j], acc[i][j]);
    __syncthreads();
    if (kt+1 < nk) STAGE_TILE(kt+1);
  }
#undef STAGE_TILE

  if (EPI == 0) {
    int which = n0 >> 10;
    #pragma unroll
    for (int i=0;i<4;i++) {
      #pragma unroll
      for (int j=0;j<4;j++) {
        int n = n0 + wc*64 + j*16 + lr;
        int hd = n & 1023, h = hd >> 6, d = hd & 63;
        #pragma unroll
        for (int r=0;r<4;r++) {
          int m = m0 + wr*64 + i*16 + lg*4 + r;
          int b = m >> 11, s = m & 2047;
          size_t bh = (size_t)(b*HH + h);
          if (which == 0)      Qp [(bh*SS + s)*DD + d] = (bf16_t)(acc[i][j][r] * QSCALE);
          else if (which == 1) Kp [(bh*SS + s)*DD + d] = (bf16_t)acc[i][j][r];
          else                 Vtp[(bh*DD + d)*SS + s] = (bf16_t)acc[i][j][r];
        }
      }
    }
  } else {
    float bv[4];
    #pragma unroll
    for (int j=0;j<4;j++) bv[j] = bias[n0 + wc*64 + j*16 + lr];
    #pragma unroll
    for (int i=0;i<4;i++)
      #pragma unroll
      for (int j=0;j<4;j++) {
        int n = n0 + wc*64 + j*16 + lr;
        #pragma unroll
        for (int r=0;r<4;r++) {
          int m = m0 + wr*64 + i*16 + lg*4 + r;
          Cout[(size_t)m*HD + n] = acc[i][j][r] + bv[j];
        }
      }
  }
}

// ---------- flash attention (causal), v3 ----------
// Q pre-scaled by (1/sqrt(D))*log2e -> softmax in exp2 domain (v_exp_f32 is 2^x).
// Row-sum of P via mfma(P, ones) into persistent accumulator (slot r == row lg*4+r).
// Defer-max: rescale only when wave-wide max growth > 8 (log2) -> rare branch.
__global__ __launch_bounds__(512)
void k_attn(const bf16_t* __restrict__ Q, const bf16_t* __restrict__ K,
            const bf16_t* __restrict__ Vt, bf16_t* __restrict__ AO) {
  __shared__ __align__(16) bf16_t Ks[2][64*64];
  __shared__ __align__(16) bf16_t Vs[2][64*64];
  __shared__ __align__(16) bf16_t P[8][16][72];

  // XCD swizzle: all 8 pair-blocks of one bh on one XCD
  int id = blockIdx.x;
  int m8 = id & 7, d8 = id >> 3;
  int bh = m8*8 + (d8 >> 3);
  int u  = d8 & 7;

  int tid = threadIdx.x, lane = tid & 63, w = tid >> 6;
  int lr = lane & 15, lg = lane >> 4;
  const bf16_t* Qb = Q  + (size_t)bh * SS * DD;
  const bf16_t* Kp = K  + (size_t)bh * SS * DD;
  const bf16_t* Vp = Vt + (size_t)bh * DD * SS;
  int b = bh >> 4, h = bh & 15;

  // staging: thread tid owns LDS chunk tid (16B): row tid>>3, slot tid&7.
  // stored slot s holds global chunk s ^ (row&7) (XOR involution; reads do same XOR)
  int srow = tid >> 3;
  int gchunk = (tid & 7) ^ (srow & 7);

  bf16x8 onesf;
  #pragma unroll
  for (int i=0;i<8;i++) onesf[i] = (bf16_t)1.0f;

#define STAGE_KV(t, buf) do { \
    int kv0_ = (t)*64; \
    gload_lds16(Kp + (size_t)(kv0_ + srow)*DD + gchunk*8, (char*)Ks[buf] + w*1024); \
    gload_lds16(Vp + (size_t)srow*SS + kv0_ + gchunk*8,   (char*)Vs[buf] + w*1024); \
  } while(0)

  for (int ph = 0; ph < 2; ++ph) {
    int p = ph ? (15 - u) : u;
    int nt = 2*p + 2;            // even -> next phase's STAGE(0)->buf0 is safe
    int qrow0 = p*128 + w*16;

    bf16x8 qf[2];
    #pragma unroll
    for (int kk=0;kk<2;kk++)
      qf[kk] = *reinterpret_cast<const bf16x8*>(Qb + (size_t)(qrow0 + lr)*DD + kk*32 + lg*8);

    f32x4 po[4];
    #pragma unroll
    for (int i=0;i<4;i++) po[i] = (f32x4){0.f,0.f,0.f,0.f};
    f32x4 accl = (f32x4){0.f,0.f,0.f,0.f};
    float mrow[4] = {NEG_INF, NEG_INF, NEG_INF, NEG_INF};

    STAGE_KV(0, 0);
    for (int t = 0; t < nt; ++t) {
      __syncthreads();                      // tile t staged & everyone done with buf t-2
      if (t+1 < nt) STAGE_KV(t+1, (t+1)&1);
      const bf16_t* Kb = Ks[t&1];
      const bf16_t* Vb = Vs[t&1];
      int kv0 = t*64;
      if (kv0 > qrow0 + 15) continue;       // fully masked for this wave

      // ---- S = Q K^T (exp2 domain; Q pre-scaled) ----
      f32x4 sa[4];
      #pragma unroll
      for (int ct=0; ct<4; ++ct) {
        int rr = ct*16 + lr;
        int sw = rr & 7;
        bf16x8 k0 = *reinterpret_cast<const bf16x8*>(Kb + rr*64 + ((lg     ^ sw) << 3));
        bf16x8 k1 = *reinterpret_cast<const bf16x8*>(Kb + rr*64 + (((4+lg) ^ sw) << 3));
        f32x4 c = (f32x4){0.f,0.f,0.f,0.f};
        c = MFMA16(qf[0], k0, c);
        c = MFMA16(qf[1], k1, c);
        sa[ct] = c;
      }
      if (kv0 + 63 > qrow0) {               // tile crosses diagonal for this wave
        #pragma unroll
        for (int ct=0;ct<4;ct++) {
          int col = kv0 + ct*16 + lr;
          #pragma unroll
          for (int r=0;r<4;r++) {
            int row = qrow0 + lg*4 + r;
            if (col > row) sa[ct][r] = NEG_INF;
          }
        }
      }
      // ---- row max (16-lane groups) + defer-max ----
      float tm[4];
      #pragma unroll
      for (int r=0;r<4;r++) {
        float v = fmaxf(fmaxf(sa[0][r], sa[1][r]), fmaxf(sa[2][r], sa[3][r]));
        v = fmaxf(v, __shfl_xor(v, 1));
        v = fmaxf(v, __shfl_xor(v, 2));
        v = fmaxf(v, __shfl_xor(v, 4));
        v = fmaxf(v, __shfl_xor(v, 8));
        tm[r] = v;
      }
      float g = fmaxf(fmaxf(tm[0]-mrow[0], tm[1]-mrow[1]),
                      fmaxf(tm[2]-mrow[2], tm[3]-mrow[3]));
      if (!__all(g <= 8.0f)) {              // wave-uniform rare branch
        #pragma unroll
        for (int r=0;r<4;r++) {
          float mn = fmaxf(mrow[r], tm[r]);
          float fs = __builtin_amdgcn_exp2f(mrow[r] - mn);
          mrow[r] = mn;
          accl[r] *= fs;
          #pragma unroll
          for (int i=0;i<4;i++) po[i][r] *= fs;
        }
      }
      // ---- P = exp2(S - m), bf16, via per-wave LDS (C-layout -> A-operand) ----
      #pragma unroll
      for (int ct=0;ct<4;ct++)
        #pragma unroll
        for (int r=0;r<4;r++)
          P[w][lg*4+r][ct*16+lr] = (bf16_t)__builtin_amdgcn_exp2f(sa[ct][r] - mrow[r]);
      // ---- O += P V ; l += rowsum(P) via mfma(P, ones) ----
      #pragma unroll
      for (int kk=0;kk<2;kk++) {
        bf16x8 pf = *reinterpret_cast<const bf16x8*>(&P[w][lr][kk*32 + lg*8]);
        accl = MFMA16(pf, onesf, accl);
        #pragma unroll
        for (int ctd=0;ctd<4;ctd++) {
          int rr = ctd*16 + lr;
          bf16x8 vf = *reinterpret_cast<const bf16x8*>(Vb + rr*64 + (((kk*4+lg) ^ (rr&7)) << 3));
          po[ctd] = MFMA16(pf, vf, po[ctd]);
        }
      }
    }
    // ---- epilogue: O /= l, concat-head layout [B*S, H*D] bf16 ----
    #pragma unroll
    for (int r=0;r<4;r++) {
      float inv = 1.0f / accl[r];
      int m = b*SS + qrow0 + lg*4 + r;
      bf16_t* dst = AO + (size_t)m*HD + h*DD;
      #pragma unroll
      for (int ctd=0;ctd<4;ctd++) dst[ctd*16 + lr] = (bf16_t)(po[ctd][r] * inv);
    }
  }
#undef STAGE_KV
}

extern "C" void kernel_launch(void* const* d_in, const int* in_sizes, int n_in,
                              void* d_out, int out_size, void* d_ws, size_t ws_size,
                              hipStream_t stream) {
  const float* x  = (const float*)d_in[0];
  const float* Wq = (const float*)d_in[1];
  const float* Wk = (const float*)d_in[2];
  const float* Wv = (const float*)d_in[3];
  const float* Wo = (const float*)d_in[4];
  const float* bo = (const float*)d_in[5];
  float* out = (float*)d_out;

  char* ws = (char*)d_ws;
  bf16_t* xb  = (bf16_t*)(ws + 0);          // [8192,1024]        16 MB
  bf16_t* wt  = (bf16_t*)(ws + 16777216);   // [3072,1024]         6 MB
  bf16_t* wob = (bf16_t*)(ws + 23068672);   // [1024,1024]         2 MB
  bf16_t* Qb  = (bf16_t*)(ws + 25165824);   // [B,H,S,D]          16 MB
  bf16_t* Kb  = (bf16_t*)(ws + 41943040);   // [B,H,S,D]          16 MB
  bf16_t* Vtb = (bf16_t*)(ws + 58720256);   // [B,H,D,S]          16 MB
  bf16_t* AO  = (bf16_t*)(ws + 75497472);   // [8192,1024]        16 MB

  k_f32_to_bf16<<<(MM*EE/8)/256, 256, 0, stream>>>(x,  xb,  MM*EE/8);
  k_f32_to_bf16<<<(EE*EE/8)/256, 256, 0, stream>>>(Wo, wob, EE*EE/8);
  dim3 gw(48, 16);
  k_conv_wqkv<<<gw, 256, 0, stream>>>(Wq, Wk, Wv, wt);

  dim3 g1(NQKV/128, MM/128);    // (24, 64)
  k_gemm<0><<<g1, 256, 0, stream>>>(xb, wt, Qb, Kb, Vtb, nullptr, nullptr, EE);

  k_attn<<<BB*HH*8, 512, 0, stream>>>(Qb, Kb, Vtb, AO);

  dim3 g3(HD/128, MM/128);      // (8, 64)
  k_gemm<1><<<g3, 256, 0, stream>>>(AO, wob, nullptr, nullptr, nullptr, bo, out, HD);
}

// Round 4
// 223.920 us; speedup vs baseline: 2.6294x; 1.0090x over previous
//
#include <hip/hip_runtime.h>
#include <hip/hip_bf16.h>

#define BB 4
#define SS 2048
#define EE 1024
#define HH 16
#define DD 64
#define MM (BB*SS)     // 8192
#define HD (HH*DD)     // 1024
#define NQKV (3*HD)    // 3072

typedef __bf16 bf16_t;
typedef __bf16 bf16x8 __attribute__((ext_vector_type(8)));
typedef float f32x4 __attribute__((ext_vector_type(4)));

#define MFMA16(a,b,c) __builtin_amdgcn_mfma_f32_16x16x32_bf16(a,b,c,0,0,0)
#define NEG_INF (-__builtin_huge_valf())
#define QSCALE 0.1803368801111204f   // (1/sqrt(64)) * log2(e): softmax runs in exp2 domain

__device__ __forceinline__ void gload_lds16(const void* g, void* l) {
  __builtin_amdgcn_global_load_lds((const __attribute__((address_space(1))) unsigned int*)g,
                                   (__attribute__((address_space(3))) unsigned int*)l,
                                   16, 0, 0);
}

#define SBAR() __builtin_amdgcn_s_barrier()
#define VMCNT2 do { asm volatile("s_waitcnt vmcnt(2)" ::: "memory"); } while(0)
#define VMCNT0 do { asm volatile("s_waitcnt vmcnt(0)" ::: "memory"); } while(0)

// ---------- f32 -> bf16, 8 elems/thread ----------
__global__ __launch_bounds__(256)
void k_f32_to_bf16(const float* __restrict__ in, bf16_t* __restrict__ out, int n8) {
  int i = blockIdx.x*256 + threadIdx.x;
  if (i >= n8) return;
  const float4* p = reinterpret_cast<const float4*>(in) + (size_t)i*2;
  float4 a = p[0], b = p[1];
  bf16x8 o;
  o[0]=(bf16_t)a.x; o[1]=(bf16_t)a.y; o[2]=(bf16_t)a.z; o[3]=(bf16_t)a.w;
  o[4]=(bf16_t)b.x; o[5]=(bf16_t)b.y; o[6]=(bf16_t)b.z; o[7]=(bf16_t)b.w;
  *reinterpret_cast<bf16x8*>(out + (size_t)i*8) = o;
}

// ---------- Wq/Wk/Wv [H,E,D] f32 -> Wt [3*H*D, E] bf16 (B^T layout) ----------
__global__ __launch_bounds__(256)
void k_conv_wqkv(const float* __restrict__ Wq, const float* __restrict__ Wk,
                 const float* __restrict__ Wv, bf16_t* __restrict__ Wt) {
  __shared__ float t[64][65];
  int wh = blockIdx.x;             // which*16 + h
  int which = wh >> 4, h = wh & 15;
  int e0 = blockIdx.y * 64;
  const float* W = (which==0) ? Wq : (which==1) ? Wk : Wv;
  const float* src = W + (size_t)h*EE*DD;
  int r = threadIdx.x >> 6, c = threadIdx.x & 63;
  #pragma unroll
  for (int i = 0; i < 16; ++i) {
    int e = i*4 + r;
    t[e][c] = src[(size_t)(e0+e)*DD + c];
  }
  __syncthreads();
  bf16_t* dst = Wt + (size_t)(which*HD + h*DD)*EE;
  #pragma unroll
  for (int i = 0; i < 16; ++i) {
    int d = i*4 + r;
    dst[(size_t)d*EE + e0 + c] = (bf16_t)t[c][d];
  }
}

// ---------- QKV GEMM: 256x256 tile, BK=64, 8 waves, 8-phase counted-vmcnt ----------
// A [8192,1024] bf16 rm; Bt [3072,1024] bf16 rm (B^T). Scatter epilogue: Q(scaled),K,V^T.
// LDS swizzle: within each 128B row, 16B chunk slot s holds global chunk s ^ (row&7);
// staged via inverse-swizzled GLOBAL source (linear LDS dest), read with same XOR.
#define QK_NT 16        // K-tiles of 64
#define QK_ITERS 8
__global__ __launch_bounds__(512, 1)
void k_gemm_qkv(const bf16_t* __restrict__ Ag, const bf16_t* __restrict__ Bg0,
                bf16_t* __restrict__ Qp, bf16_t* __restrict__ Kp, bf16_t* __restrict__ Vtp) {
  __shared__ __align__(16) bf16_t Ab[2][256*64];   // 2 x 32KB
  __shared__ __align__(16) bf16_t Bb[2][256*64];   // 2 x 32KB  -> 128KB total

  // XCD-aware bijective swizzle: 384 wgs, 48 per XCD chunk
  int orig = blockIdx.x;
  int wg = (orig & 7) * 48 + (orig >> 3);
  int tileX = wg % 12, tileY = wg / 12;
  int n0 = tileX * 256, m0 = tileY * 256;

  int tid = threadIdx.x;
  int lane = tid & 63, w = tid >> 6;
  int wr = w >> 2, wc = w & 3;          // 2 x 4 wave grid; wave tile 128x64
  int lr = lane & 15, lg = lane >> 4;

  const bf16_t* Bg = Bg0 + (size_t)n0 * EE;

  // staging constants: thread covers chunk (L*512+tid): row r3+L*64 (+half*128), slot tid&7
  int r3 = tid >> 3;
  int gch = (tid & 7) ^ (r3 & 7);
  int ldsb = (tid >> 6) * 1024;         // wave-uniform base; HW adds lane*16

#define STAGE_A(buf, kt, half) do { \
    const bf16_t* g_ = Ag + (size_t)(m0 + (half)*128 + r3)*EE + (kt)*64 + gch*8; \
    char* l_ = (char*)Ab[buf] + (half)*16384 + ldsb; \
    gload_lds16(g_, l_); \
    gload_lds16(g_ + (size_t)64*EE, l_ + 8192); \
  } while(0)
#define STAGE_B(buf, kt, half) do { \
    const bf16_t* g_ = Bg + (size_t)((half)*128 + r3)*EE + (kt)*64 + gch*8; \
    char* l_ = (char*)Bb[buf] + (half)*16384 + ldsb; \
    gload_lds16(g_, l_); \
    gload_lds16(g_ + (size_t)64*EE, l_ + 8192); \
  } while(0)

  // frag read bases (byte offsets into a 32KB tile); row&7 == lr&7 for all frags
  int sA = lr & 7;
  unsigned aoff[2] = { (unsigned)((wr*128 + lr)*128 + ((lg     ^ sA) << 4)),
                       (unsigned)((wr*128 + lr)*128 + (((4+lg) ^ sA) << 4)) };
  unsigned boff[2] = { (unsigned)((wc*64  + lr)*128 + ((lg     ^ sA) << 4)),
                       (unsigned)((wc*64  + lr)*128 + (((4+lg) ^ sA) << 4)) };

  f32x4 acc[8][4];
  #pragma unroll
  for (int i=0;i<8;i++)
    #pragma unroll
    for (int j=0;j<4;j++) acc[i][j] = (f32x4){0.f,0.f,0.f,0.f};
  bf16x8 af[8], b0, b1;

#define PHASE(buf, kh, nh, WAITV, ...) do { \
    if ((nh) == 0) { \
      _Pragma("unroll") for (int mf_=0; mf_<8; ++mf_) \
        af[mf_] = *reinterpret_cast<const bf16x8*>((const char*)Ab[buf] + aoff[kh] + mf_*2048); \
    } \
    b0 = *reinterpret_cast<const bf16x8*>((const char*)Bb[buf] + boff[kh] + (nh)*4096); \
    b1 = *reinterpret_cast<const bf16x8*>((const char*)Bb[buf] + boff[kh] + (nh)*4096 + 2048); \
    __VA_ARGS__; \
    SBAR(); \
    asm volatile("s_waitcnt lgkmcnt(0)" ::: "memory"); \
    __builtin_amdgcn_sched_barrier(0); \
    __builtin_amdgcn_s_setprio(1); \
    _Pragma("unroll") for (int mf_=0; mf_<8; ++mf_) { \
      acc[mf_][(nh)*2+0] = MFMA16(af[mf_], b0, acc[mf_][(nh)*2+0]); \
      acc[mf_][(nh)*2+1] = MFMA16(af[mf_], b1, acc[mf_][(nh)*2+1]); } \
    __builtin_amdgcn_s_setprio(0); \
    WAITV; \
    SBAR(); \
    __builtin_amdgcn_sched_barrier(0); \
  } while(0)

  // prologue: T0 full into buf0, T1 A-h0 into buf1; first 4 stages must land
  STAGE_A(0, 0, 0); STAGE_A(0, 0, 1);
  STAGE_B(0, 0, 0); STAGE_B(0, 0, 1);
  STAGE_A(1, 1, 0);
  VMCNT2;
  SBAR();
  __builtin_amdgcn_sched_barrier(0);

#define WAITQ { if (!last) { VMCNT2; } else { VMCNT0; } }
  for (int i = 0; i < QK_ITERS; ++i) {
    int t1 = 2*i+1, t2 = 2*i+2, t3 = 2*i+3;
    bool last = (i == QK_ITERS-1);
    // phases 0-3: consume buf0 (tile 2i); stage buf1 tail of T(2i+1), then buf0 <- T(2i+2)
    PHASE(0, 0, 0, (void)0, STAGE_A(1, t1, 1));
    PHASE(0, 0, 1, (void)0, STAGE_B(1, t1, 0));
    PHASE(0, 1, 0, (void)0, STAGE_B(1, t1, 1));
    PHASE(0, 1, 1, WAITQ,   if (!last) STAGE_A(0, t2, 0));
    // phases 4-7: consume buf1 (tile 2i+1); finish buf0 <- T(2i+2); start buf1 <- T(2i+3)
    PHASE(1, 0, 0, (void)0, if (!last) STAGE_A(0, t2, 1));
    PHASE(1, 0, 1, (void)0, if (!last) STAGE_B(0, t2, 0));
    PHASE(1, 1, 0, (void)0, if (!last) STAGE_B(0, t2, 1));
    PHASE(1, 1, 1, WAITQ,   if (!last) STAGE_A(1, t3, 0));
  }
#undef WAITQ
#undef PHASE
#undef STAGE_A
#undef STAGE_B

  // epilogue: scatter Q (scaled), K, V^T — bf16
  int which = n0 >> 10;   // uniform per block (256-tile never crosses a 1024 boundary)
  #pragma unroll
  for (int mf=0; mf<8; ++mf) {
    #pragma unroll
    for (int nf=0; nf<4; ++nf) {
      int n = n0 + wc*64 + nf*16 + lr;
      int hd = n & 1023, h2 = hd >> 6, d = hd & 63;
      #pragma unroll
      for (int r=0;r<4;r++) {
        int m = m0 + wr*128 + mf*16 + lg*4 + r;
        int b = m >> 11, s = m & 2047;
        size_t bh = (size_t)(b*HH + h2);
        if (which == 0)      Qp [(bh*SS + s)*DD + d] = (bf16_t)(acc[mf][nf][r] * QSCALE);
        else if (which == 1) Kp [(bh*SS + s)*DD + d] = (bf16_t)acc[mf][nf][r];
        else                 Vtp[(bh*DD + d)*SS + s] = (bf16_t)acc[mf][nf][r];
      }
    }
  }
}

// ---------- proj GEMM: C[M,N] = A[M,K] * Bt[N,K]^T + bias (f32 out) ----------
template<int EPI>
__global__ __launch_bounds__(256)
void k_gemm(const bf16_t* __restrict__ A, const bf16_t* __restrict__ Bt,
            bf16_t* __restrict__ Qp, bf16_t* __restrict__ Kp, bf16_t* __restrict__ Vtp,
            const float* __restrict__ bias, float* __restrict__ Cout, int Kdim) {
  __shared__ __align__(16) bf16_t As[128*32];
  __shared__ __align__(16) bf16_t Bs[128*32];
  int m0 = blockIdx.y * 128, n0 = blockIdx.x * 128;
  int tid = threadIdx.x;
  int lane = tid & 63, w = tid >> 6;
  int wr = w >> 1, wc = w & 1;
  int lr = lane & 15, lg = lane >> 4;

  f32x4 acc[4][4];
  #pragma unroll
  for (int i=0;i<4;i++)
    #pragma unroll
    for (int j=0;j<4;j++) acc[i][j] = (f32x4){0.f,0.f,0.f,0.f};

  const int nk = Kdim >> 5;
  int srow = tid >> 2;            // 0..63
  int scol = (tid & 3) << 3;      // 0,8,16,24

#define STAGE_TILE(kt) do { \
    const bf16_t* Ab_ = A  + (size_t)m0*Kdim + ((kt)<<5); \
    const bf16_t* Bb_ = Bt + (size_t)n0*Kdim + ((kt)<<5); \
    _Pragma("unroll") \
    for (int j_ = 0; j_ < 2; ++j_) { \
      int row_ = j_*64 + srow; \
      unsigned off_ = (unsigned)(j_*4096 + w*1024); \
      gload_lds16(Ab_ + (size_t)row_*Kdim + scol, (char*)As + off_); \
      gload_lds16(Bb_ + (size_t)row_*Kdim + scol, (char*)Bs + off_); \
    } \
  } while(0)

  STAGE_TILE(0);
  for (int kt = 0; kt < nk; ++kt) {
    __syncthreads();
    bf16x8 af[4], bf[4];
    #pragma unroll
    for (int i=0;i<4;i++) {
      af[i] = *reinterpret_cast<const bf16x8*>(As + ((wr*64 + i*16 + lr)<<5) + (lg<<3));
      bf[i] = *reinterpret_cast<const bf16x8*>(Bs + ((wc*64 + i*16 + lr)<<5) + (lg<<3));
    }
    #pragma unroll
    for (int i=0;i<4;i++)
      #pragma unroll
      for (int j=0;j<4;j++)
        acc[i][j] = MFMA16(af[i], bf[j], acc[i][j]);
    __syncthreads();
    if (kt+1 < nk) STAGE_TILE(kt+1);
  }
#undef STAGE_TILE

  {
    float bv[4];
    #pragma unroll
    for (int j=0;j<4;j++) bv[j] = bias[n0 + wc*64 + j*16 + lr];
    #pragma unroll
    for (int i=0;i<4;i++)
      #pragma unroll
      for (int j=0;j<4;j++) {
        int n = n0 + wc*64 + j*16 + lr;
        #pragma unroll
        for (int r=0;r<4;r++) {
          int m = m0 + wr*64 + i*16 + lg*4 + r;
          Cout[(size_t)m*HD + n] = acc[i][j][r] + bv[j];
        }
      }
  }
}

// ---------- flash attention (causal), v3 ----------
__global__ __launch_bounds__(512)
void k_attn(const bf16_t* __restrict__ Q, const bf16_t* __restrict__ K,
            const bf16_t* __restrict__ Vt, bf16_t* __restrict__ AO) {
  __shared__ __align__(16) bf16_t Ks[2][64*64];
  __shared__ __align__(16) bf16_t Vs[2][64*64];
  __shared__ __align__(16) bf16_t P[8][16][72];

  int id = blockIdx.x;
  int m8 = id & 7, d8 = id >> 3;
  int bh = m8*8 + (d8 >> 3);
  int u  = d8 & 7;

  int tid = threadIdx.x, lane = tid & 63, w = tid >> 6;
  int lr = lane & 15, lg = lane >> 4;
  const bf16_t* Qb = Q  + (size_t)bh * SS * DD;
  const bf16_t* Kp = K  + (size_t)bh * SS * DD;
  const bf16_t* Vp = Vt + (size_t)bh * DD * SS;
  int b = bh >> 4, h = bh & 15;

  int srow = tid >> 3;
  int gchunk = (tid & 7) ^ (srow & 7);

  bf16x8 onesf;
  #pragma unroll
  for (int i=0;i<8;i++) onesf[i] = (bf16_t)1.0f;

#define STAGE_KV(t, buf) do { \
    int kv0_ = (t)*64; \
    gload_lds16(Kp + (size_t)(kv0_ + srow)*DD + gchunk*8, (char*)Ks[buf] + w*1024); \
    gload_lds16(Vp + (size_t)srow*SS + kv0_ + gchunk*8,   (char*)Vs[buf] + w*1024); \
  } while(0)

  for (int ph = 0; ph < 2; ++ph) {
    int p = ph ? (15 - u) : u;
    int nt = 2*p + 2;
    int qrow0 = p*128 + w*16;

    bf16x8 qf[2];
    #pragma unroll
    for (int kk=0;kk<2;kk++)
      qf[kk] = *reinterpret_cast<const bf16x8*>(Qb + (size_t)(qrow0 + lr)*DD + kk*32 + lg*8);

    f32x4 po[4];
    #pragma unroll
    for (int i=0;i<4;i++) po[i] = (f32x4){0.f,0.f,0.f,0.f};
    f32x4 accl = (f32x4){0.f,0.f,0.f,0.f};
    float mrow[4] = {NEG_INF, NEG_INF, NEG_INF, NEG_INF};

    STAGE_KV(0, 0);
    for (int t = 0; t < nt; ++t) {
      __syncthreads();
      if (t+1 < nt) STAGE_KV(t+1, (t+1)&1);
      const bf16_t* Kb = Ks[t&1];
      const bf16_t* Vb = Vs[t&1];
      int kv0 = t*64;
      if (kv0 > qrow0 + 15) continue;

      f32x4 sa[4];
      #pragma unroll
      for (int ct=0; ct<4; ++ct) {
        int rr = ct*16 + lr;
        int sw = rr & 7;
        bf16x8 k0 = *reinterpret_cast<const bf16x8*>(Kb + rr*64 + ((lg     ^ sw) << 3));
        bf16x8 k1 = *reinterpret_cast<const bf16x8*>(Kb + rr*64 + (((4+lg) ^ sw) << 3));
        f32x4 c = (f32x4){0.f,0.f,0.f,0.f};
        c = MFMA16(qf[0], k0, c);
        c = MFMA16(qf[1], k1, c);
        sa[ct] = c;
      }
      if (kv0 + 63 > qrow0) {
        #pragma unroll
        for (int ct=0;ct<4;ct++) {
          int col = kv0 + ct*16 + lr;
          #pragma unroll
          for (int r=0;r<4;r++) {
            int row = qrow0 + lg*4 + r;
            if (col > row) sa[ct][r] = NEG_INF;
          }
        }
      }
      float tm[4];
      #pragma unroll
      for (int r=0;r<4;r++) {
        float v = fmaxf(fmaxf(sa[0][r], sa[1][r]), fmaxf(sa[2][r], sa[3][r]));
        v = fmaxf(v, __shfl_xor(v, 1));
        v = fmaxf(v, __shfl_xor(v, 2));
        v = fmaxf(v, __shfl_xor(v, 4));
        v = fmaxf(v, __shfl_xor(v, 8));
        tm[r] = v;
      }
      float g = fmaxf(fmaxf(tm[0]-mrow[0], tm[1]-mrow[1]),
                      fmaxf(tm[2]-mrow[2], tm[3]-mrow[3]));
      if (!__all(g <= 8.0f)) {
        #pragma unroll
        for (int r=0;r<4;r++) {
          float mn = fmaxf(mrow[r], tm[r]);
          float fs = __builtin_amdgcn_exp2f(mrow[r] - mn);
          mrow[r] = mn;
          accl[r] *= fs;
          #pragma unroll
          for (int i=0;i<4;i++) po[i][r] *= fs;
        }
      }
      #pragma unroll
      for (int ct=0;ct<4;ct++)
        #pragma unroll
        for (int r=0;r<4;r++)
          P[w][lg*4+r][ct*16+lr] = (bf16_t)__builtin_amdgcn_exp2f(sa[ct][r] - mrow[r]);
      #pragma unroll
      for (int kk=0;kk<2;kk++) {
        bf16x8 pf = *reinterpret_cast<const bf16x8*>(&P[w][lr][kk*32 + lg*8]);
        accl = MFMA16(pf, onesf, accl);
        #pragma unroll
        for (int ctd=0;ctd<4;ctd++) {
          int rr = ctd*16 + lr;
          bf16x8 vf = *reinterpret_cast<const bf16x8*>(Vb + rr*64 + (((kk*4+lg) ^ (rr&7)) << 3));
          po[ctd] = MFMA16(pf, vf, po[ctd]);
        }
      }
    }
    #pragma unroll
    for (int r=0;r<4;r++) {
      float inv = 1.0f / accl[r];
      int m = b*SS + qrow0 + lg*4 + r;
      bf16_t* dst = AO + (size_t)m*HD + h*DD;
      #pragma unroll
      for (int ctd=0;ctd<4;ctd++) dst[ctd*16 + lr] = (bf16_t)(po[ctd][r] * inv);
    }
  }
#undef STAGE_KV
}

extern "C" void kernel_launch(void* const* d_in, const int* in_sizes, int n_in,
                              void* d_out, int out_size, void* d_ws, size_t ws_size,
                              hipStream_t stream) {
  const float* x  = (const float*)d_in[0];
  const float* Wq = (const float*)d_in[1];
  const float* Wk = (const float*)d_in[2];
  const float* Wv = (const float*)d_in[3];
  const float* Wo = (const float*)d_in[4];
  const float* bo = (const float*)d_in[5];
  float* out = (float*)d_out;

  char* ws = (char*)d_ws;
  bf16_t* xb  = (bf16_t*)(ws + 0);          // [8192,1024]        16 MB
  bf16_t* wt  = (bf16_t*)(ws + 16777216);   // [3072,1024]         6 MB
  bf16_t* wob = (bf16_t*)(ws + 23068672);   // [1024,1024]         2 MB
  bf16_t* Qb  = (bf16_t*)(ws + 25165824);   // [B,H,S,D]          16 MB
  bf16_t* Kb  = (bf16_t*)(ws + 41943040);   // [B,H,S,D]          16 MB
  bf16_t* Vtb = (bf16_t*)(ws + 58720256);   // [B,H,D,S]          16 MB
  bf16_t* AO  = (bf16_t*)(ws + 75497472);   // [8192,1024]        16 MB

  k_f32_to_bf16<<<(MM*EE/8)/256, 256, 0, stream>>>(x,  xb,  MM*EE/8);
  k_f32_to_bf16<<<(EE*EE/8)/256, 256, 0, stream>>>(Wo, wob, EE*EE/8);
  dim3 gw(48, 16);
  k_conv_wqkv<<<gw, 256, 0, stream>>>(Wq, Wk, Wv, wt);

  k_gemm_qkv<<<384, 512, 0, stream>>>(xb, wt, Qb, Kb, Vtb);

  k_attn<<<BB*HH*8, 512, 0, stream>>>(Qb, Kb, Vtb, AO);

  dim3 g3(HD/128, MM/128);      // (8, 64)
  k_gemm<1><<<g3, 256, 0, stream>>>(AO, wob, nullptr, nullptr, nullptr, bo, out, HD);
}

// Round 5
// 201.601 us; speedup vs baseline: 2.9205x; 1.1107x over previous
//
#include <hip/hip_runtime.h>
#include <hip/hip_bf16.h>

#define BB 4
#define SS 2048
#define EE 1024
#define HH 16
#define DD 64
#define MM (BB*SS)     // 8192
#define HD (HH*DD)     // 1024
#define NQKV (3*HD)    // 3072

typedef __bf16 bf16_t;
typedef __bf16 bf16x4 __attribute__((ext_vector_type(4)));
typedef __bf16 bf16x8 __attribute__((ext_vector_type(8)));
typedef float f32x4 __attribute__((ext_vector_type(4)));

#define MFMA16(a,b,c) __builtin_amdgcn_mfma_f32_16x16x32_bf16(a,b,c,0,0,0)
#define NEG_INF (-__builtin_huge_valf())
#define QSCALE 0.1803368801111204f   // (1/sqrt(64)) * log2(e): softmax runs in exp2 domain

__device__ __forceinline__ void gload_lds16(const void* g, void* l) {
  __builtin_amdgcn_global_load_lds((const __attribute__((address_space(1))) unsigned int*)g,
                                   (__attribute__((address_space(3))) unsigned int*)l,
                                   16, 0, 0);
}

#define SBAR() __builtin_amdgcn_s_barrier()
#define VMCNT2 do { asm volatile("s_waitcnt vmcnt(2)" ::: "memory"); } while(0)
#define VMCNT0 do { asm volatile("s_waitcnt vmcnt(0)" ::: "memory"); } while(0)

// ---------- f32 -> bf16, 8 elems/thread ----------
__global__ __launch_bounds__(256)
void k_f32_to_bf16(const float* __restrict__ in, bf16_t* __restrict__ out, int n8) {
  int i = blockIdx.x*256 + threadIdx.x;
  if (i >= n8) return;
  const float4* p = reinterpret_cast<const float4*>(in) + (size_t)i*2;
  float4 a = p[0], b = p[1];
  bf16x8 o;
  o[0]=(bf16_t)a.x; o[1]=(bf16_t)a.y; o[2]=(bf16_t)a.z; o[3]=(bf16_t)a.w;
  o[4]=(bf16_t)b.x; o[5]=(bf16_t)b.y; o[6]=(bf16_t)b.z; o[7]=(bf16_t)b.w;
  *reinterpret_cast<bf16x8*>(out + (size_t)i*8) = o;
}

// ---------- Wq/Wk/Wv [H,E,D] f32 -> Wt [3*H*D, E] bf16 (B^T layout) ----------
__global__ __launch_bounds__(256)
void k_conv_wqkv(const float* __restrict__ Wq, const float* __restrict__ Wk,
                 const float* __restrict__ Wv, bf16_t* __restrict__ Wt) {
  __shared__ float t[64][65];
  int wh = blockIdx.x;             // which*16 + h
  int which = wh >> 4, h = wh & 15;
  int e0 = blockIdx.y * 64;
  const float* W = (which==0) ? Wq : (which==1) ? Wk : Wv;
  const float* src = W + (size_t)h*EE*DD;
  int r = threadIdx.x >> 6, c = threadIdx.x & 63;
  #pragma unroll
  for (int i = 0; i < 16; ++i) {
    int e = i*4 + r;
    t[e][c] = src[(size_t)(e0+e)*DD + c];
  }
  __syncthreads();
  bf16_t* dst = Wt + (size_t)(which*HD + h*DD)*EE;
  #pragma unroll
  for (int i = 0; i < 16; ++i) {
    int d = i*4 + r;
    dst[(size_t)d*EE + e0 + c] = (bf16_t)t[c][d];
  }
}

// ---------- QKV GEMM: 256x256 tile, BK=64, 8 waves, 8-phase counted-vmcnt ----------
#define QK_ITERS 8
__global__ __launch_bounds__(512, 1)
void k_gemm_qkv(const bf16_t* __restrict__ Ag, const bf16_t* __restrict__ Bg0,
                bf16_t* __restrict__ Qp, bf16_t* __restrict__ Kp, bf16_t* __restrict__ Vtp) {
  __shared__ __align__(16) bf16_t Ab[2][256*64];   // 2 x 32KB
  __shared__ __align__(16) bf16_t Bb[2][256*64];   // 2 x 32KB  -> 128KB total

  // XCD-aware bijective swizzle: 384 wgs, 48 per XCD chunk
  int orig = blockIdx.x;
  int wg = (orig & 7) * 48 + (orig >> 3);
  int tileX = wg % 12, tileY = wg / 12;
  int n0 = tileX * 256, m0 = tileY * 256;

  int tid = threadIdx.x;
  int lane = tid & 63, w = tid >> 6;
  int wr = w >> 2, wc = w & 3;          // 2 x 4 wave grid; wave tile 128x64
  int lr = lane & 15, lg = lane >> 4;

  const bf16_t* Bg = Bg0 + (size_t)n0 * EE;

  // staging: thread covers chunk (L*512+tid): row r3+L*64 (+half*128), slot tid&7
  int r3 = tid >> 3;
  int gch = (tid & 7) ^ (r3 & 7);
  int ldsb = (tid >> 6) * 1024;         // wave-uniform base; HW adds lane*16

#define STAGE_A(buf, kt, half) do { \
    const bf16_t* g_ = Ag + (size_t)(m0 + (half)*128 + r3)*EE + (kt)*64 + gch*8; \
    char* l_ = (char*)Ab[buf] + (half)*16384 + ldsb; \
    gload_lds16(g_, l_); \
    gload_lds16(g_ + (size_t)64*EE, l_ + 8192); \
  } while(0)
#define STAGE_B(buf, kt, half) do { \
    const bf16_t* g_ = Bg + (size_t)((half)*128 + r3)*EE + (kt)*64 + gch*8; \
    char* l_ = (char*)Bb[buf] + (half)*16384 + ldsb; \
    gload_lds16(g_, l_); \
    gload_lds16(g_ + (size_t)64*EE, l_ + 8192); \
  } while(0)

  // frag read bases (byte offsets into a 32KB tile); row&7 == lr&7 for all frags
  int sA = lr & 7;
  unsigned aoff[2] = { (unsigned)((wr*128 + lr)*128 + ((lg     ^ sA) << 4)),
                       (unsigned)((wr*128 + lr)*128 + (((4+lg) ^ sA) << 4)) };
  unsigned boff[2] = { (unsigned)((wc*64  + lr)*128 + ((lg     ^ sA) << 4)),
                       (unsigned)((wc*64  + lr)*128 + (((4+lg) ^ sA) << 4)) };

  f32x4 acc[8][4];
  #pragma unroll
  for (int i=0;i<8;i++)
    #pragma unroll
    for (int j=0;j<4;j++) acc[i][j] = (f32x4){0.f,0.f,0.f,0.f};
  bf16x8 af[8], b0, b1;

#define PHASE(buf, kh, nh, WAITV, ...) do { \
    if ((nh) == 0) { \
      _Pragma("unroll") for (int mf_=0; mf_<8; ++mf_) \
        af[mf_] = *reinterpret_cast<const bf16x8*>((const char*)Ab[buf] + aoff[kh] + mf_*2048); \
    } \
    b0 = *reinterpret_cast<const bf16x8*>((const char*)Bb[buf] + boff[kh] + (nh)*4096); \
    b1 = *reinterpret_cast<const bf16x8*>((const char*)Bb[buf] + boff[kh] + (nh)*4096 + 2048); \
    __VA_ARGS__; \
    SBAR(); \
    asm volatile("s_waitcnt lgkmcnt(0)" ::: "memory"); \
    __builtin_amdgcn_sched_barrier(0); \
    __builtin_amdgcn_s_setprio(1); \
    _Pragma("unroll") for (int mf_=0; mf_<8; ++mf_) { \
      acc[mf_][(nh)*2+0] = MFMA16(af[mf_], b0, acc[mf_][(nh)*2+0]); \
      acc[mf_][(nh)*2+1] = MFMA16(af[mf_], b1, acc[mf_][(nh)*2+1]); } \
    __builtin_amdgcn_s_setprio(0); \
    WAITV; \
    SBAR(); \
    __builtin_amdgcn_sched_barrier(0); \
  } while(0)

  // prologue: T0 full into buf0, T1 A-h0 into buf1; first 4 stages must land
  STAGE_A(0, 0, 0); STAGE_A(0, 0, 1);
  STAGE_B(0, 0, 0); STAGE_B(0, 0, 1);
  STAGE_A(1, 1, 0);
  VMCNT2;
  SBAR();
  __builtin_amdgcn_sched_barrier(0);

#define WAITQ { if (!last) { VMCNT2; } else { VMCNT0; } }
  for (int i = 0; i < QK_ITERS; ++i) {
    int t1 = 2*i+1, t2 = 2*i+2, t3 = 2*i+3;
    bool last = (i == QK_ITERS-1);
    PHASE(0, 0, 0, (void)0, STAGE_A(1, t1, 1));
    PHASE(0, 0, 1, (void)0, STAGE_B(1, t1, 0));
    PHASE(0, 1, 0, (void)0, STAGE_B(1, t1, 1));
    PHASE(0, 1, 1, WAITQ,   if (!last) STAGE_A(0, t2, 0));
    PHASE(1, 0, 0, (void)0, if (!last) STAGE_A(0, t2, 1));
    PHASE(1, 0, 1, (void)0, if (!last) STAGE_B(0, t2, 0));
    PHASE(1, 1, 0, (void)0, if (!last) STAGE_B(0, t2, 1));
    PHASE(1, 1, 1, WAITQ,   if (!last) STAGE_A(1, t3, 0));
  }
#undef WAITQ
#undef PHASE
#undef STAGE_A
#undef STAGE_B

  // epilogue
  int which = n0 >> 10;   // uniform per block (256-tile never crosses a 1024 boundary)
  if (which < 2) {
    #pragma unroll
    for (int mf=0; mf<8; ++mf) {
      #pragma unroll
      for (int nf=0; nf<4; ++nf) {
        int n = n0 + wc*64 + nf*16 + lr;
        int hd = n & 1023, h2 = hd >> 6, d = hd & 63;
        #pragma unroll
        for (int r=0;r<4;r++) {
          int m = m0 + wr*128 + mf*16 + lg*4 + r;
          int b = m >> 11, s = m & 2047;
          size_t bh = (size_t)(b*HH + h2);
          if (which == 0)      Qp[(bh*SS + s)*DD + d] = (bf16_t)(acc[mf][nf][r] * QSCALE);
          else                 Kp[(bh*SS + s)*DD + d] = (bf16_t)acc[mf][nf][r];
        }
      }
    }
  } else {
    // V^T: thread holds 4 CONSECUTIVE s-values per (mf,nf) -> one 8B bf16x4 store
    // (16 rows x contiguous 32B segments per wave-instr vs 2B scatter before)
    #pragma unroll
    for (int mf=0; mf<8; ++mf) {
      #pragma unroll
      for (int nf=0; nf<4; ++nf) {
        int n = n0 + wc*64 + nf*16 + lr;
        int hd = n & 1023, h2 = hd >> 6, d = hd & 63;
        int m = m0 + wr*128 + mf*16 + lg*4;      // s base, multiple of 4
        int b = m >> 11, s = m & 2047;
        size_t bh = (size_t)(b*HH + h2);
        bf16x4 vv;
        vv[0] = (bf16_t)acc[mf][nf][0];
        vv[1] = (bf16_t)acc[mf][nf][1];
        vv[2] = (bf16_t)acc[mf][nf][2];
        vv[3] = (bf16_t)acc[mf][nf][3];
        *reinterpret_cast<bf16x4*>(Vtp + (bh*DD + d)*SS + s) = vv;
      }
    }
  }
}

// ---------- proj GEMM: C[M,N] = A[M,K] * Bt[N,K]^T + bias (f32 out) ----------
template<int EPI>
__global__ __launch_bounds__(256)
void k_gemm(const bf16_t* __restrict__ A, const bf16_t* __restrict__ Bt,
            bf16_t* __restrict__ Qp, bf16_t* __restrict__ Kp, bf16_t* __restrict__ Vtp,
            const float* __restrict__ bias, float* __restrict__ Cout, int Kdim) {
  __shared__ __align__(16) bf16_t As[128*32];
  __shared__ __align__(16) bf16_t Bs[128*32];
  int m0 = blockIdx.y * 128, n0 = blockIdx.x * 128;
  int tid = threadIdx.x;
  int lane = tid & 63, w = tid >> 6;
  int wr = w >> 1, wc = w & 1;
  int lr = lane & 15, lg = lane >> 4;

  f32x4 acc[4][4];
  #pragma unroll
  for (int i=0;i<4;i++)
    #pragma unroll
    for (int j=0;j<4;j++) acc[i][j] = (f32x4){0.f,0.f,0.f,0.f};

  const int nk = Kdim >> 5;
  int srow = tid >> 2;            // 0..63
  int scol = (tid & 3) << 3;      // 0,8,16,24

#define STAGE_TILE(kt) do { \
    const bf16_t* Ab_ = A  + (size_t)m0*Kdim + ((kt)<<5); \
    const bf16_t* Bb_ = Bt + (size_t)n0*Kdim + ((kt)<<5); \
    _Pragma("unroll") \
    for (int j_ = 0; j_ < 2; ++j_) { \
      int row_ = j_*64 + srow; \
      unsigned off_ = (unsigned)(j_*4096 + w*1024); \
      gload_lds16(Ab_ + (size_t)row_*Kdim + scol, (char*)As + off_); \
      gload_lds16(Bb_ + (size_t)row_*Kdim + scol, (char*)Bs + off_); \
    } \
  } while(0)

  STAGE_TILE(0);
  for (int kt = 0; kt < nk; ++kt) {
    __syncthreads();
    bf16x8 af[4], bf[4];
    #pragma unroll
    for (int i=0;i<4;i++) {
      af[i] = *reinterpret_cast<const bf16x8*>(As + ((wr*64 + i*16 + lr)<<5) + (lg<<3));
      bf[i] = *reinterpret_cast<const bf16x8*>(Bs + ((wc*64 + i*16 + lr)<<5) + (lg<<3));
    }
    #pragma unroll
    for (int i=0;i<4;i++)
      #pragma unroll
      for (int j=0;j<4;j++)
        acc[i][j] = MFMA16(af[i], bf[j], acc[i][j]);
    __syncthreads();
    if (kt+1 < nk) STAGE_TILE(kt+1);
  }
#undef STAGE_TILE

  {
    float bv[4];
    #pragma unroll
    for (int j=0;j<4;j++) bv[j] = bias[n0 + wc*64 + j*16 + lr];
    #pragma unroll
    for (int i=0;i<4;i++)
      #pragma unroll
      for (int j=0;j<4;j++) {
        int n = n0 + wc*64 + j*16 + lr;
        #pragma unroll
        for (int r=0;r<4;r++) {
          int m = m0 + wr*64 + i*16 + lg*4 + r;
          Cout[(size_t)m*HD + n] = acc[i][j][r] + bv[j];
        }
      }
  }
}

// ---------- flash attention (causal), v3 ----------
__global__ __launch_bounds__(512)
void k_attn(const bf16_t* __restrict__ Q, const bf16_t* __restrict__ K,
            const bf16_t* __restrict__ Vt, bf16_t* __restrict__ AO) {
  __shared__ __align__(16) bf16_t Ks[2][64*64];
  __shared__ __align__(16) bf16_t Vs[2][64*64];
  __shared__ __align__(16) bf16_t P[8][16][72];

  int id = blockIdx.x;
  int m8 = id & 7, d8 = id >> 3;
  int bh = m8*8 + (d8 >> 3);
  int u  = d8 & 7;

  int tid = threadIdx.x, lane = tid & 63, w = tid >> 6;
  int lr = lane & 15, lg = lane >> 4;
  const bf16_t* Qb = Q  + (size_t)bh * SS * DD;
  const bf16_t* Kp = K  + (size_t)bh * SS * DD;
  const bf16_t* Vp = Vt + (size_t)bh * DD * SS;
  int b = bh >> 4, h = bh & 15;

  int srow = tid >> 3;
  int gchunk = (tid & 7) ^ (srow & 7);

  bf16x8 onesf;
  #pragma unroll
  for (int i=0;i<8;i++) onesf[i] = (bf16_t)1.0f;

#define STAGE_KV(t, buf) do { \
    int kv0_ = (t)*64; \
    gload_lds16(Kp + (size_t)(kv0_ + srow)*DD + gchunk*8, (char*)Ks[buf] + w*1024); \
    gload_lds16(Vp + (size_t)srow*SS + kv0_ + gchunk*8,   (char*)Vs[buf] + w*1024); \
  } while(0)

  for (int ph = 0; ph < 2; ++ph) {
    int p = ph ? (15 - u) : u;
    int nt = 2*p + 2;
    int qrow0 = p*128 + w*16;

    bf16x8 qf[2];
    #pragma unroll
    for (int kk=0;kk<2;kk++)
      qf[kk] = *reinterpret_cast<const bf16x8*>(Qb + (size_t)(qrow0 + lr)*DD + kk*32 + lg*8);

    f32x4 po[4];
    #pragma unroll
    for (int i=0;i<4;i++) po[i] = (f32x4){0.f,0.f,0.f,0.f};
    f32x4 accl = (f32x4){0.f,0.f,0.f,0.f};
    float mrow[4] = {NEG_INF, NEG_INF, NEG_INF, NEG_INF};

    STAGE_KV(0, 0);
    for (int t = 0; t < nt; ++t) {
      __syncthreads();
      if (t+1 < nt) STAGE_KV(t+1, (t+1)&1);
      const bf16_t* Kb = Ks[t&1];
      const bf16_t* Vb = Vs[t&1];
      int kv0 = t*64;
      if (kv0 > qrow0 + 15) continue;

      f32x4 sa[4];
      #pragma unroll
      for (int ct=0; ct<4; ++ct) {
        int rr = ct*16 + lr;
        int sw = rr & 7;
        bf16x8 k0 = *reinterpret_cast<const bf16x8*>(Kb + rr*64 + ((lg     ^ sw) << 3));
        bf16x8 k1 = *reinterpret_cast<const bf16x8*>(Kb + rr*64 + (((4+lg) ^ sw) << 3));
        f32x4 c = (f32x4){0.f,0.f,0.f,0.f};
        c = MFMA16(qf[0], k0, c);
        c = MFMA16(qf[1], k1, c);
        sa[ct] = c;
      }
      if (kv0 + 63 > qrow0) {
        #pragma unroll
        for (int ct=0;ct<4;ct++) {
          int col = kv0 + ct*16 + lr;
          #pragma unroll
          for (int r=0;r<4;r++) {
            int row = qrow0 + lg*4 + r;
            if (col > row) sa[ct][r] = NEG_INF;
          }
        }
      }
      float tm[4];
      #pragma unroll
      for (int r=0;r<4;r++) {
        float v = fmaxf(fmaxf(sa[0][r], sa[1][r]), fmaxf(sa[2][r], sa[3][r]));
        v = fmaxf(v, __shfl_xor(v, 1));
        v = fmaxf(v, __shfl_xor(v, 2));
        v = fmaxf(v, __shfl_xor(v, 4));
        v = fmaxf(v, __shfl_xor(v, 8));
        tm[r] = v;
      }
      float g = fmaxf(fmaxf(tm[0]-mrow[0], tm[1]-mrow[1]),
                      fmaxf(tm[2]-mrow[2], tm[3]-mrow[3]));
      if (!__all(g <= 8.0f)) {
        #pragma unroll
        for (int r=0;r<4;r++) {
          float mn = fmaxf(mrow[r], tm[r]);
          float fs = __builtin_amdgcn_exp2f(mrow[r] - mn);
          mrow[r] = mn;
          accl[r] *= fs;
          #pragma unroll
          for (int i=0;i<4;i++) po[i][r] *= fs;
        }
      }
      #pragma unroll
      for (int ct=0;ct<4;ct++)
        #pragma unroll
        for (int r=0;r<4;r++)
          P[w][lg*4+r][ct*16+lr] = (bf16_t)__builtin_amdgcn_exp2f(sa[ct][r] - mrow[r]);
      #pragma unroll
      for (int kk=0;kk<2;kk++) {
        bf16x8 pf = *reinterpret_cast<const bf16x8*>(&P[w][lr][kk*32 + lg*8]);
        accl = MFMA16(pf, onesf, accl);
        #pragma unroll
        for (int ctd=0;ctd<4;ctd++) {
          int rr = ctd*16 + lr;
          bf16x8 vf = *reinterpret_cast<const bf16x8*>(Vb + rr*64 + (((kk*4+lg) ^ (rr&7)) << 3));
          po[ctd] = MFMA16(pf, vf, po[ctd]);
        }
      }
    }
    #pragma unroll
    for (int r=0;r<4;r++) {
      float inv = 1.0f / accl[r];
      int m = b*SS + qrow0 + lg*4 + r;
      bf16_t* dst = AO + (size_t)m*HD + h*DD;
      #pragma unroll
      for (int ctd=0;ctd<4;ctd++) dst[ctd*16 + lr] = (bf16_t)(po[ctd][r] * inv);
    }
  }
#undef STAGE_KV
}

extern "C" void kernel_launch(void* const* d_in, const int* in_sizes, int n_in,
                              void* d_out, int out_size, void* d_ws, size_t ws_size,
                              hipStream_t stream) {
  const float* x  = (const float*)d_in[0];
  const float* Wq = (const float*)d_in[1];
  const float* Wk = (const float*)d_in[2];
  const float* Wv = (const float*)d_in[3];
  const float* Wo = (const float*)d_in[4];
  const float* bo = (const float*)d_in[5];
  float* out = (float*)d_out;

  char* ws = (char*)d_ws;
  bf16_t* xb  = (bf16_t*)(ws + 0);          // [8192,1024]        16 MB
  bf16_t* wt  = (bf16_t*)(ws + 16777216);   // [3072,1024]         6 MB
  bf16_t* wob = (bf16_t*)(ws + 23068672);   // [1024,1024]         2 MB
  bf16_t* Qb  = (bf16_t*)(ws + 25165824);   // [B,H,S,D]          16 MB
  bf16_t* Kb  = (bf16_t*)(ws + 41943040);   // [B,H,S,D]          16 MB
  bf16_t* Vtb = (bf16_t*)(ws + 58720256);   // [B,H,D,S]          16 MB
  bf16_t* AO  = (bf16_t*)(ws + 75497472);   // [8192,1024]        16 MB

  k_f32_to_bf16<<<(MM*EE/8)/256, 256, 0, stream>>>(x,  xb,  MM*EE/8);
  k_f32_to_bf16<<<(EE*EE/8)/256, 256, 0, stream>>>(Wo, wob, EE*EE/8);
  dim3 gw(48, 16);
  k_conv_wqkv<<<gw, 256, 0, stream>>>(Wq, Wk, Wv, wt);

  k_gemm_qkv<<<384, 512, 0, stream>>>(xb, wt, Qb, Kb, Vtb);

  k_attn<<<BB*HH*8, 512, 0, stream>>>(Qb, Kb, Vtb, AO);

  dim3 g3(HD/128, MM/128);      // (8, 64)
  k_gemm<1><<<g3, 256, 0, stream>>>(AO, wob, nullptr, nullptr, nullptr, bo, out, HD);
}

// Round 6
// 188.441 us; speedup vs baseline: 3.1245x; 1.0698x over previous
//
#include <hip/hip_runtime.h>
#include <hip/hip_bf16.h>

#define BB 4
#define SS 2048
#define EE 1024
#define HH 16
#define DD 64
#define MM (BB*SS)     // 8192
#define HD (HH*DD)     // 1024
#define NQKV (3*HD)    // 3072

typedef __bf16 bf16_t;
typedef __bf16 bf16x4 __attribute__((ext_vector_type(4)));
typedef __bf16 bf16x8 __attribute__((ext_vector_type(8)));
typedef float f32x4 __attribute__((ext_vector_type(4)));

#define MFMA16(a,b,c) __builtin_amdgcn_mfma_f32_16x16x32_bf16(a,b,c,0,0,0)
#define NEG_INF (-__builtin_huge_valf())
#define QSCALE 0.1803368801111204f   // (1/sqrt(64)) * log2(e): softmax runs in exp2 domain

__device__ __forceinline__ void gload_lds16(const void* g, void* l) {
  __builtin_amdgcn_global_load_lds((const __attribute__((address_space(1))) unsigned int*)g,
                                   (__attribute__((address_space(3))) unsigned int*)l,
                                   16, 0, 0);
}

#define SBAR() __builtin_amdgcn_s_barrier()
#define VMCNT2 do { asm volatile("s_waitcnt vmcnt(2)" ::: "memory"); } while(0)
#define VMCNT0 do { asm volatile("s_waitcnt vmcnt(0)" ::: "memory"); } while(0)

// ---------- f32 -> bf16, 8 elems/thread ----------
__global__ __launch_bounds__(256)
void k_f32_to_bf16(const float* __restrict__ in, bf16_t* __restrict__ out, int n8) {
  int i = blockIdx.x*256 + threadIdx.x;
  if (i >= n8) return;
  const float4* p = reinterpret_cast<const float4*>(in) + (size_t)i*2;
  float4 a = p[0], b = p[1];
  bf16x8 o;
  o[0]=(bf16_t)a.x; o[1]=(bf16_t)a.y; o[2]=(bf16_t)a.z; o[3]=(bf16_t)a.w;
  o[4]=(bf16_t)b.x; o[5]=(bf16_t)b.y; o[6]=(bf16_t)b.z; o[7]=(bf16_t)b.w;
  *reinterpret_cast<bf16x8*>(out + (size_t)i*8) = o;
}

// ---------- Wq/Wk/Wv [H,E,D] f32 -> Wt [3*H*D, E] bf16 (B^T layout) ----------
__global__ __launch_bounds__(256)
void k_conv_wqkv(const float* __restrict__ Wq, const float* __restrict__ Wk,
                 const float* __restrict__ Wv, bf16_t* __restrict__ Wt) {
  __shared__ float t[64][65];
  int wh = blockIdx.x;             // which*16 + h
  int which = wh >> 4, h = wh & 15;
  int e0 = blockIdx.y * 64;
  const float* W = (which==0) ? Wq : (which==1) ? Wk : Wv;
  const float* src = W + (size_t)h*EE*DD;
  int r = threadIdx.x >> 6, c = threadIdx.x & 63;
  #pragma unroll
  for (int i = 0; i < 16; ++i) {
    int e = i*4 + r;
    t[e][c] = src[(size_t)(e0+e)*DD + c];
  }
  __syncthreads();
  bf16_t* dst = Wt + (size_t)(which*HD + h*DD)*EE;
  #pragma unroll
  for (int i = 0; i < 16; ++i) {
    int d = i*4 + r;
    dst[(size_t)d*EE + e0 + c] = (bf16_t)t[c][d];
  }
}

// ---------- QKV GEMM: 256x256 tile, BK=64, 8 waves, 8-phase counted-vmcnt ----------
#define QK_ITERS 8
__global__ __launch_bounds__(512, 1)
void k_gemm_qkv(const bf16_t* __restrict__ Ag, const bf16_t* __restrict__ Bg0,
                bf16_t* __restrict__ Qp, bf16_t* __restrict__ Kp, bf16_t* __restrict__ Vtp) {
  __shared__ __align__(16) bf16_t Ab[2][256*64];   // 2 x 32KB
  __shared__ __align__(16) bf16_t Bb[2][256*64];   // 2 x 32KB  -> 128KB total

  // XCD-aware bijective swizzle: 384 wgs, 48 per XCD chunk
  int orig = blockIdx.x;
  int wg = (orig & 7) * 48 + (orig >> 3);
  int tileX = wg % 12, tileY = wg / 12;
  int n0 = tileX * 256, m0 = tileY * 256;

  int tid = threadIdx.x;
  int lane = tid & 63, w = tid >> 6;
  int wr = w >> 2, wc = w & 3;          // 2 x 4 wave grid; wave tile 128x64
  int lr = lane & 15, lg = lane >> 4;

  const bf16_t* Bg = Bg0 + (size_t)n0 * EE;

  // staging: thread covers chunk (L*512+tid): row r3+L*64 (+half*128), slot tid&7
  int r3 = tid >> 3;
  int gch = (tid & 7) ^ (r3 & 7);
  int ldsb = (tid >> 6) * 1024;         // wave-uniform base; HW adds lane*16

#define STAGE_A(buf, kt, half) do { \
    const bf16_t* g_ = Ag + (size_t)(m0 + (half)*128 + r3)*EE + (kt)*64 + gch*8; \
    char* l_ = (char*)Ab[buf] + (half)*16384 + ldsb; \
    gload_lds16(g_, l_); \
    gload_lds16(g_ + (size_t)64*EE, l_ + 8192); \
  } while(0)
#define STAGE_B(buf, kt, half) do { \
    const bf16_t* g_ = Bg + (size_t)((half)*128 + r3)*EE + (kt)*64 + gch*8; \
    char* l_ = (char*)Bb[buf] + (half)*16384 + ldsb; \
    gload_lds16(g_, l_); \
    gload_lds16(g_ + (size_t)64*EE, l_ + 8192); \
  } while(0)

  // frag read bases (byte offsets into a 32KB tile); row&7 == lr&7 for all frags
  int sA = lr & 7;
  unsigned aoff[2] = { (unsigned)((wr*128 + lr)*128 + ((lg     ^ sA) << 4)),
                       (unsigned)((wr*128 + lr)*128 + (((4+lg) ^ sA) << 4)) };
  unsigned boff[2] = { (unsigned)((wc*64  + lr)*128 + ((lg     ^ sA) << 4)),
                       (unsigned)((wc*64  + lr)*128 + (((4+lg) ^ sA) << 4)) };

  f32x4 acc[8][4];
  #pragma unroll
  for (int i=0;i<8;i++)
    #pragma unroll
    for (int j=0;j<4;j++) acc[i][j] = (f32x4){0.f,0.f,0.f,0.f};
  bf16x8 af[8], b0, b1;

#define PHASE(buf, kh, nh, WAITV, ...) do { \
    if ((nh) == 0) { \
      _Pragma("unroll") for (int mf_=0; mf_<8; ++mf_) \
        af[mf_] = *reinterpret_cast<const bf16x8*>((const char*)Ab[buf] + aoff[kh] + mf_*2048); \
    } \
    b0 = *reinterpret_cast<const bf16x8*>((const char*)Bb[buf] + boff[kh] + (nh)*4096); \
    b1 = *reinterpret_cast<const bf16x8*>((const char*)Bb[buf] + boff[kh] + (nh)*4096 + 2048); \
    __VA_ARGS__; \
    SBAR(); \
    asm volatile("s_waitcnt lgkmcnt(0)" ::: "memory"); \
    __builtin_amdgcn_sched_barrier(0); \
    __builtin_amdgcn_s_setprio(1); \
    _Pragma("unroll") for (int mf_=0; mf_<8; ++mf_) { \
      acc[mf_][(nh)*2+0] = MFMA16(af[mf_], b0, acc[mf_][(nh)*2+0]); \
      acc[mf_][(nh)*2+1] = MFMA16(af[mf_], b1, acc[mf_][(nh)*2+1]); } \
    __builtin_amdgcn_s_setprio(0); \
    WAITV; \
    SBAR(); \
    __builtin_amdgcn_sched_barrier(0); \
  } while(0)

  // prologue: T0 full into buf0, T1 A-h0 into buf1; first 4 stages must land
  STAGE_A(0, 0, 0); STAGE_A(0, 0, 1);
  STAGE_B(0, 0, 0); STAGE_B(0, 0, 1);
  STAGE_A(1, 1, 0);
  VMCNT2;
  SBAR();
  __builtin_amdgcn_sched_barrier(0);

#define WAITQ { if (!last) { VMCNT2; } else { VMCNT0; } }
  for (int i = 0; i < QK_ITERS; ++i) {
    int t1 = 2*i+1, t2 = 2*i+2, t3 = 2*i+3;
    bool last = (i == QK_ITERS-1);
    PHASE(0, 0, 0, (void)0, STAGE_A(1, t1, 1));
    PHASE(0, 0, 1, (void)0, STAGE_B(1, t1, 0));
    PHASE(0, 1, 0, (void)0, STAGE_B(1, t1, 1));
    PHASE(0, 1, 1, WAITQ,   if (!last) STAGE_A(0, t2, 0));
    PHASE(1, 0, 0, (void)0, if (!last) STAGE_A(0, t2, 1));
    PHASE(1, 0, 1, (void)0, if (!last) STAGE_B(0, t2, 0));
    PHASE(1, 1, 0, (void)0, if (!last) STAGE_B(0, t2, 1));
    PHASE(1, 1, 1, WAITQ,   if (!last) STAGE_A(1, t3, 0));
  }
#undef WAITQ
#undef PHASE
#undef STAGE_A
#undef STAGE_B

  // epilogue
  int which = n0 >> 10;   // uniform per block (256-tile never crosses a 1024 boundary)
  if (which < 2) {
    #pragma unroll
    for (int mf=0; mf<8; ++mf) {
      #pragma unroll
      for (int nf=0; nf<4; ++nf) {
        int n = n0 + wc*64 + nf*16 + lr;
        int hd = n & 1023, h2 = hd >> 6, d = hd & 63;
        #pragma unroll
        for (int r=0;r<4;r++) {
          int m = m0 + wr*128 + mf*16 + lg*4 + r;
          int b = m >> 11, s = m & 2047;
          size_t bh = (size_t)(b*HH + h2);
          if (which == 0)      Qp[(bh*SS + s)*DD + d] = (bf16_t)(acc[mf][nf][r] * QSCALE);
          else                 Kp[(bh*SS + s)*DD + d] = (bf16_t)acc[mf][nf][r];
        }
      }
    }
  } else {
    // V^T: thread holds 4 CONSECUTIVE s-values per (mf,nf) -> one 8B bf16x4 store
    #pragma unroll
    for (int mf=0; mf<8; ++mf) {
      #pragma unroll
      for (int nf=0; nf<4; ++nf) {
        int n = n0 + wc*64 + nf*16 + lr;
        int hd = n & 1023, h2 = hd >> 6, d = hd & 63;
        int m = m0 + wr*128 + mf*16 + lg*4;      // s base, multiple of 4
        int b = m >> 11, s = m & 2047;
        size_t bh = (size_t)(b*HH + h2);
        bf16x4 vv;
        vv[0] = (bf16_t)acc[mf][nf][0];
        vv[1] = (bf16_t)acc[mf][nf][1];
        vv[2] = (bf16_t)acc[mf][nf][2];
        vv[3] = (bf16_t)acc[mf][nf][3];
        *reinterpret_cast<bf16x4*>(Vtp + (bh*DD + d)*SS + s) = vv;
      }
    }
  }
}

// ---------- proj GEMM: C[M,N] = A[M,K] * Bt[N,K]^T + bias (f32 out) ----------
template<int EPI>
__global__ __launch_bounds__(256)
void k_gemm(const bf16_t* __restrict__ A, const bf16_t* __restrict__ Bt,
            bf16_t* __restrict__ Qp, bf16_t* __restrict__ Kp, bf16_t* __restrict__ Vtp,
            const float* __restrict__ bias, float* __restrict__ Cout, int Kdim) {
  __shared__ __align__(16) bf16_t As[128*32];
  __shared__ __align__(16) bf16_t Bs[128*32];
  int m0 = blockIdx.y * 128, n0 = blockIdx.x * 128;
  int tid = threadIdx.x;
  int lane = tid & 63, w = tid >> 6;
  int wr = w >> 1, wc = w & 1;
  int lr = lane & 15, lg = lane >> 4;

  f32x4 acc[4][4];
  #pragma unroll
  for (int i=0;i<4;i++)
    #pragma unroll
    for (int j=0;j<4;j++) acc[i][j] = (f32x4){0.f,0.f,0.f,0.f};

  const int nk = Kdim >> 5;
  int srow = tid >> 2;            // 0..63
  int scol = (tid & 3) << 3;      // 0,8,16,24

#define STAGE_TILE(kt) do { \
    const bf16_t* Ab_ = A  + (size_t)m0*Kdim + ((kt)<<5); \
    const bf16_t* Bb_ = Bt + (size_t)n0*Kdim + ((kt)<<5); \
    _Pragma("unroll") \
    for (int j_ = 0; j_ < 2; ++j_) { \
      int row_ = j_*64 + srow; \
      unsigned off_ = (unsigned)(j_*4096 + w*1024); \
      gload_lds16(Ab_ + (size_t)row_*Kdim + scol, (char*)As + off_); \
      gload_lds16(Bb_ + (size_t)row_*Kdim + scol, (char*)Bs + off_); \
    } \
  } while(0)

  STAGE_TILE(0);
  for (int kt = 0; kt < nk; ++kt) {
    __syncthreads();
    bf16x8 af[4], bf[4];
    #pragma unroll
    for (int i=0;i<4;i++) {
      af[i] = *reinterpret_cast<const bf16x8*>(As + ((wr*64 + i*16 + lr)<<5) + (lg<<3));
      bf[i] = *reinterpret_cast<const bf16x8*>(Bs + ((wc*64 + i*16 + lr)<<5) + (lg<<3));
    }
    #pragma unroll
    for (int i=0;i<4;i++)
      #pragma unroll
      for (int j=0;j<4;j++)
        acc[i][j] = MFMA16(af[i], bf[j], acc[i][j]);
    __syncthreads();
    if (kt+1 < nk) STAGE_TILE(kt+1);
  }
#undef STAGE_TILE

  {
    float bv[4];
    #pragma unroll
    for (int j=0;j<4;j++) bv[j] = bias[n0 + wc*64 + j*16 + lr];
    #pragma unroll
    for (int i=0;i<4;i++)
      #pragma unroll
      for (int j=0;j<4;j++) {
        int n = n0 + wc*64 + j*16 + lr;
        #pragma unroll
        for (int r=0;r<4;r++) {
          int m = m0 + wr*64 + i*16 + lg*4 + r;
          Cout[(size_t)m*HD + n] = acc[i][j][r] + bv[j];
        }
      }
  }
}

// ---------- flash attention (causal), v4: swapped QK^T, in-register P ----------
// S^T = mfma(K,Q): lane holds one q-column (q=qrow0+lr), 16 kv values
// (kv=ct*16+lg*4+r). Softmax reduce = 15 local + shfl_xor(16,32). P^T stays in
// registers as the PV B-operand (k-perm sigma(lg,j)=ct*16+lg*4+j); V^T frags read
// as 2x ds_read_b64 from swizzled Vs. Output is O^T (lane owns one q row).
__global__ __launch_bounds__(512)
void k_attn(const bf16_t* __restrict__ Q, const bf16_t* __restrict__ K,
            const bf16_t* __restrict__ Vt, bf16_t* __restrict__ AO) {
  __shared__ __align__(16) bf16_t Ks[2][64*64];
  __shared__ __align__(16) bf16_t Vs[2][64*64];

  int id = blockIdx.x;
  int m8 = id & 7, d8 = id >> 3;
  int bh = m8*8 + (d8 >> 3);
  int u  = d8 & 7;

  int tid = threadIdx.x, lane = tid & 63, w = tid >> 6;
  int lr = lane & 15, lg = lane >> 4;
  const bf16_t* Qb = Q  + (size_t)bh * SS * DD;
  const bf16_t* Kp = K  + (size_t)bh * SS * DD;
  const bf16_t* Vp = Vt + (size_t)bh * DD * SS;
  int b = bh >> 4, h = bh & 15;

  int srow = tid >> 3;
  int gchunk = (tid & 7) ^ (srow & 7);

#define STAGE_KV(t, buf) do { \
    int kv0_ = (t)*64; \
    gload_lds16(Kp + (size_t)(kv0_ + srow)*DD + gchunk*8, (char*)Ks[buf] + w*1024); \
    gload_lds16(Vp + (size_t)srow*SS + kv0_ + gchunk*8,   (char*)Vs[buf] + w*1024); \
  } while(0)

  for (int ph = 0; ph < 2; ++ph) {
    int p = ph ? (15 - u) : u;
    int nt = 2*p + 2;
    int qrow0 = p*128 + w*16;
    int q = qrow0 + lr;               // this lane's q row

    bf16x8 qf[2];
    #pragma unroll
    for (int kk=0;kk<2;kk++)
      qf[kk] = *reinterpret_cast<const bf16x8*>(Qb + (size_t)(qrow0 + lr)*DD + kk*32 + lg*8);

    f32x4 po[4];                      // O^T: po[ctd][r] = O[q][d=ctd*16+lg*4+r]
    #pragma unroll
    for (int i=0;i<4;i++) po[i] = (f32x4){0.f,0.f,0.f,0.f};
    float accl = 0.f;
    float mrun = NEG_INF;

    STAGE_KV(0, 0);
    for (int t = 0; t < nt; ++t) {
      __syncthreads();
      if (t+1 < nt) STAGE_KV(t+1, (t+1)&1);
      const bf16_t* Kb = Ks[t&1];
      const bf16_t* Vb = Vs[t&1];
      int kv0 = t*64;
      if (kv0 > qrow0 + 15) continue;

      // ---- S^T = K Q^T : sa[ct][r] = S[q][kv0+ct*16+lg*4+r] ----
      f32x4 sa[4];
      #pragma unroll
      for (int ct=0; ct<4; ++ct) {
        int rr = ct*16 + lr;
        int sw = rr & 7;
        bf16x8 k0 = *reinterpret_cast<const bf16x8*>(Kb + rr*64 + ((lg     ^ sw) << 3));
        bf16x8 k1 = *reinterpret_cast<const bf16x8*>(Kb + rr*64 + (((4+lg) ^ sw) << 3));
        f32x4 c = (f32x4){0.f,0.f,0.f,0.f};
        c = MFMA16(k0, qf[0], c);
        c = MFMA16(k1, qf[1], c);
        sa[ct] = c;
      }
      if (kv0 + 63 > qrow0) {          // tile crosses diagonal for this wave
        #pragma unroll
        for (int ct=0;ct<4;ct++) {
          #pragma unroll
          for (int r=0;r<4;r++) {
            int kv = kv0 + ct*16 + lg*4 + r;
            if (kv > q) sa[ct][r] = NEG_INF;
          }
        }
      }
      // ---- column max: 15 local fmax + 2 shfl ----
      float v01 = fmaxf(fmaxf(sa[0][0],sa[0][1]), fmaxf(sa[0][2],sa[0][3]));
      float v23 = fmaxf(fmaxf(sa[1][0],sa[1][1]), fmaxf(sa[1][2],sa[1][3]));
      float v45 = fmaxf(fmaxf(sa[2][0],sa[2][1]), fmaxf(sa[2][2],sa[2][3]));
      float v67 = fmaxf(fmaxf(sa[3][0],sa[3][1]), fmaxf(sa[3][2],sa[3][3]));
      float vm = fmaxf(fmaxf(v01,v23), fmaxf(v45,v67));
      vm = fmaxf(vm, __shfl_xor(vm, 16));
      vm = fmaxf(vm, __shfl_xor(vm, 32));
      // ---- defer-max: rescale only on wave-wide growth > 8 (log2) ----
      if (!__all(vm - mrun <= 8.0f)) {
        float mn = fmaxf(mrun, vm);
        float fs = __builtin_amdgcn_exp2f(mrun - mn);
        mrun = mn;
        accl *= fs;
        #pragma unroll
        for (int i=0;i<4;i++) po[i] *= fs;
      }
      // ---- P = exp2(S - m): pack PV B-frags in registers; local row-sum ----
      bf16x8 pf[2];
      float rs = 0.f;
      #pragma unroll
      for (int ct=0;ct<4;ct++) {
        #pragma unroll
        for (int r=0;r<4;r++) {
          float pv = __builtin_amdgcn_exp2f(sa[ct][r] - mrun);
          rs += pv;
          pf[ct>>1][(ct&1)*4 + r] = (bf16_t)pv;
        }
      }
      rs += __shfl_xor(rs, 16);
      rs += __shfl_xor(rs, 32);
      accl += rs;
      // ---- O^T += V^T-frag x P^T-frag ----
      #pragma unroll
      for (int ctd=0; ctd<4; ++ctd) {
        int rr = ctd*16 + lr;
        int sw8 = rr & 7;
        int sub = (lg & 1) << 3;
        const char* rowb = (const char*)Vb + rr*128;
        #pragma unroll
        for (int kk=0; kk<2; ++kk) {
          int c0 = kk*4 + (lg>>1);
          bf16x4 lo = *reinterpret_cast<const bf16x4*>(rowb + (((c0     ^ sw8) << 4) | sub));
          bf16x4 hi = *reinterpret_cast<const bf16x4*>(rowb + ((((c0+2) ^ sw8) << 4) | sub));
          bf16x8 vf;
          vf[0]=lo[0]; vf[1]=lo[1]; vf[2]=lo[2]; vf[3]=lo[3];
          vf[4]=hi[0]; vf[5]=hi[1]; vf[6]=hi[2]; vf[7]=hi[3];
          po[ctd] = MFMA16(vf, pf[kk], po[ctd]);
        }
      }
    }
    // ---- epilogue: O /= l; lane owns q row -> 4x bf16x4 stores ----
    {
      float inv = 1.0f / accl;
      bf16_t* dst = AO + (size_t)(b*SS + q)*HD + h*DD;
      #pragma unroll
      for (int ctd=0;ctd<4;ctd++) {
        bf16x4 vv;
        #pragma unroll
        for (int r=0;r<4;r++) vv[r] = (bf16_t)(po[ctd][r] * inv);
        *reinterpret_cast<bf16x4*>(dst + ctd*16 + lg*4) = vv;
      }
    }
  }
#undef STAGE_KV
}

extern "C" void kernel_launch(void* const* d_in, const int* in_sizes, int n_in,
                              void* d_out, int out_size, void* d_ws, size_t ws_size,
                              hipStream_t stream) {
  const float* x  = (const float*)d_in[0];
  const float* Wq = (const float*)d_in[1];
  const float* Wk = (const float*)d_in[2];
  const float* Wv = (const float*)d_in[3];
  const float* Wo = (const float*)d_in[4];
  const float* bo = (const float*)d_in[5];
  float* out = (float*)d_out;

  char* ws = (char*)d_ws;
  bf16_t* xb  = (bf16_t*)(ws + 0);          // [8192,1024]        16 MB
  bf16_t* wt  = (bf16_t*)(ws + 16777216);   // [3072,1024]         6 MB
  bf16_t* wob = (bf16_t*)(ws + 23068672);   // [1024,1024]         2 MB
  bf16_t* Qb  = (bf16_t*)(ws + 25165824);   // [B,H,S,D]          16 MB
  bf16_t* Kb  = (bf16_t*)(ws + 41943040);   // [B,H,S,D]          16 MB
  bf16_t* Vtb = (bf16_t*)(ws + 58720256);   // [B,H,D,S]          16 MB
  bf16_t* AO  = (bf16_t*)(ws + 75497472);   // [8192,1024]        16 MB

  k_f32_to_bf16<<<(MM*EE/8)/256, 256, 0, stream>>>(x,  xb,  MM*EE/8);
  k_f32_to_bf16<<<(EE*EE/8)/256, 256, 0, stream>>>(Wo, wob, EE*EE/8);
  dim3 gw(48, 16);
  k_conv_wqkv<<<gw, 256, 0, stream>>>(Wq, Wk, Wv, wt);

  k_gemm_qkv<<<384, 512, 0, stream>>>(xb, wt, Qb, Kb, Vtb);

  k_attn<<<BB*HH*8, 512, 0, stream>>>(Qb, Kb, Vtb, AO);

  dim3 g3(HD/128, MM/128);      // (8, 64)
  k_gemm<1><<<g3, 256, 0, stream>>>(AO, wob, nullptr, nullptr, nullptr, bo, out, HD);
}

// Round 7
// 182.582 us; speedup vs baseline: 3.2248x; 1.0321x over previous
//
#include <hip/hip_runtime.h>
#include <hip/hip_bf16.h>

#define BB 4
#define SS 2048
#define EE 1024
#define HH 16
#define DD 64
#define MM (BB*SS)     // 8192
#define HD (HH*DD)     // 1024
#define NQKV (3*HD)    // 3072

typedef __bf16 bf16_t;
typedef __bf16 bf16x4 __attribute__((ext_vector_type(4)));
typedef __bf16 bf16x8 __attribute__((ext_vector_type(8)));
typedef float f32x4 __attribute__((ext_vector_type(4)));

#define MFMA16(a,b,c) __builtin_amdgcn_mfma_f32_16x16x32_bf16(a,b,c,0,0,0)
#define NEG_INF (-__builtin_huge_valf())
#define QSCALE 0.1803368801111204f   // (1/sqrt(64)) * log2(e): softmax runs in exp2 domain

__device__ __forceinline__ void gload_lds16(const void* g, void* l) {
  __builtin_amdgcn_global_load_lds((const __attribute__((address_space(1))) unsigned int*)g,
                                   (__attribute__((address_space(3))) unsigned int*)l,
                                   16, 0, 0);
}

#define SBAR() __builtin_amdgcn_s_barrier()
#define VMCNT2 do { asm volatile("s_waitcnt vmcnt(2)" ::: "memory"); } while(0)
#define VMCNT0 do { asm volatile("s_waitcnt vmcnt(0)" ::: "memory"); } while(0)

// ---------- f32 -> bf16, 8 elems/thread ----------
__global__ __launch_bounds__(256)
void k_f32_to_bf16(const float* __restrict__ in, bf16_t* __restrict__ out, int n8) {
  int i = blockIdx.x*256 + threadIdx.x;
  if (i >= n8) return;
  const float4* p = reinterpret_cast<const float4*>(in) + (size_t)i*2;
  float4 a = p[0], b = p[1];
  bf16x8 o;
  o[0]=(bf16_t)a.x; o[1]=(bf16_t)a.y; o[2]=(bf16_t)a.z; o[3]=(bf16_t)a.w;
  o[4]=(bf16_t)b.x; o[5]=(bf16_t)b.y; o[6]=(bf16_t)b.z; o[7]=(bf16_t)b.w;
  *reinterpret_cast<bf16x8*>(out + (size_t)i*8) = o;
}

// ---------- Wq/Wk/Wv [H,E,D] f32 -> Wt [3*H*D, E] bf16 (B^T layout) ----------
__global__ __launch_bounds__(256)
void k_conv_wqkv(const float* __restrict__ Wq, const float* __restrict__ Wk,
                 const float* __restrict__ Wv, bf16_t* __restrict__ Wt) {
  __shared__ float t[64][65];
  int wh = blockIdx.x;             // which*16 + h
  int which = wh >> 4, h = wh & 15;
  int e0 = blockIdx.y * 64;
  const float* W = (which==0) ? Wq : (which==1) ? Wk : Wv;
  const float* src = W + (size_t)h*EE*DD;
  int r = threadIdx.x >> 6, c = threadIdx.x & 63;
  #pragma unroll
  for (int i = 0; i < 16; ++i) {
    int e = i*4 + r;
    t[e][c] = src[(size_t)(e0+e)*DD + c];
  }
  __syncthreads();
  bf16_t* dst = Wt + (size_t)(which*HD + h*DD)*EE;
  #pragma unroll
  for (int i = 0; i < 16; ++i) {
    int d = i*4 + r;
    dst[(size_t)d*EE + e0 + c] = (bf16_t)t[c][d];
  }
}

// ---------- GEMM template: 128x256 tile, BK=64, 8 waves, 8-phase counted-vmcnt ----------
// A [M,1024] bf16 rm; Bt [N,1024] bf16 rm (B^T layout).
// EPI=0: scatter epilogue Q(scaled)/K/V^T, NTX=12. EPI=1: f32 + bias, NTX=4.
// Stage units per K-tile: A=1 (16KB), B=2 (16KB each); ring keeps 3 units in
// flight -> vmcnt(2) at phases 4/8 (vmcnt(0) on last iter).
#define QK_ITERS 8
template<int EPI, int NTX>
__global__ __launch_bounds__(512, 1)
void k_gemm8(const bf16_t* __restrict__ Ag, const bf16_t* __restrict__ Bg0,
             bf16_t* __restrict__ Qp, bf16_t* __restrict__ Kp, bf16_t* __restrict__ Vtp,
             const float* __restrict__ bias, float* __restrict__ Cout) {
  __shared__ __align__(16) bf16_t Ab[2][128*64];   // 2 x 16KB
  __shared__ __align__(16) bf16_t Bb[2][256*64];   // 2 x 32KB  -> 96KB total

  // XCD-aware bijective swizzle (grid % 8 == 0)
  int orig = blockIdx.x;
  int cpx = gridDim.x >> 3;
  int wg = (orig & 7) * cpx + (orig >> 3);
  int tileX = wg % NTX, tileY = wg / NTX;
  int n0 = tileX * 256, m0 = tileY * 128;

  int tid = threadIdx.x;
  int lane = tid & 63, w = tid >> 6;
  int wr = w >> 2, wc = w & 3;          // 2 x 4 wave grid; wave tile 64x64
  int lr = lane & 15, lg = lane >> 4;

  const bf16_t* Bg = Bg0 + (size_t)n0 * EE;

  // staging: thread tid covers 16B chunk: row tid>>3 (+64 for 2nd gload), slot tid&7
  int r3 = tid >> 3;
  int gch = (tid & 7) ^ (r3 & 7);
  int ldsb = w * 1024;                  // wave-uniform base; HW adds lane*16

#define STAGE_A(buf, kt) do { \
    const bf16_t* g_ = Ag + (size_t)(m0 + r3)*EE + (kt)*64 + gch*8; \
    char* l_ = (char*)Ab[buf] + ldsb; \
    gload_lds16(g_, l_); \
    gload_lds16(g_ + (size_t)64*EE, l_ + 8192); \
  } while(0)
#define STAGE_B(buf, kt, half) do { \
    const bf16_t* g_ = Bg + (size_t)((half)*128 + r3)*EE + (kt)*64 + gch*8; \
    char* l_ = (char*)Bb[buf] + (half)*16384 + ldsb; \
    gload_lds16(g_, l_); \
    gload_lds16(g_ + (size_t)64*EE, l_ + 8192); \
  } while(0)

  // frag read bases (byte offsets); row&7 == lr&7 for all frags
  int sA = lr & 7;
  unsigned aoff[2] = { (unsigned)((wr*64 + lr)*128 + ((lg     ^ sA) << 4)),
                       (unsigned)((wr*64 + lr)*128 + (((4+lg) ^ sA) << 4)) };
  unsigned boff[2] = { (unsigned)((wc*64 + lr)*128 + ((lg     ^ sA) << 4)),
                       (unsigned)((wc*64 + lr)*128 + (((4+lg) ^ sA) << 4)) };

  f32x4 acc[4][4];
  #pragma unroll
  for (int i=0;i<4;i++)
    #pragma unroll
    for (int j=0;j<4;j++) acc[i][j] = (f32x4){0.f,0.f,0.f,0.f};
  bf16x8 af[4], b0, b1;

#define PHASE(buf, kh, nh, WAITV, ...) do { \
    if ((nh) == 0) { \
      _Pragma("unroll") for (int mf_=0; mf_<4; ++mf_) \
        af[mf_] = *reinterpret_cast<const bf16x8*>((const char*)Ab[buf] + aoff[kh] + mf_*2048); \
    } \
    b0 = *reinterpret_cast<const bf16x8*>((const char*)Bb[buf] + boff[kh] + (nh)*4096); \
    b1 = *reinterpret_cast<const bf16x8*>((const char*)Bb[buf] + boff[kh] + (nh)*4096 + 2048); \
    __VA_ARGS__; \
    SBAR(); \
    asm volatile("s_waitcnt lgkmcnt(0)" ::: "memory"); \
    __builtin_amdgcn_sched_barrier(0); \
    __builtin_amdgcn_s_setprio(1); \
    _Pragma("unroll") for (int mf_=0; mf_<4; ++mf_) { \
      acc[mf_][(nh)*2+0] = MFMA16(af[mf_], b0, acc[mf_][(nh)*2+0]); \
      acc[mf_][(nh)*2+1] = MFMA16(af[mf_], b1, acc[mf_][(nh)*2+1]); } \
    __builtin_amdgcn_s_setprio(0); \
    WAITV; \
    SBAR(); \
    __builtin_amdgcn_sched_barrier(0); \
  } while(0)

  // prologue: T0 full into buf0, A(T1) into buf1; A0,B0 must land
  STAGE_A(0, 0);
  STAGE_B(0, 0, 0); STAGE_B(0, 0, 1);
  STAGE_A(1, 1);
  VMCNT2;
  SBAR();
  __builtin_amdgcn_sched_barrier(0);

#define WAITQ { if (!last) { VMCNT2; } else { VMCNT0; } }
  for (int i = 0; i < QK_ITERS; ++i) {
    int t1 = 2*i+1, t2 = 2*i+2, t3 = 2*i+3;
    bool last = (i == QK_ITERS-1);
    // phases 1-4: consume buf0 (tile 2i); stage B(t1)->buf1, A(t2)->buf0 (ph4: A last read ph3)
    PHASE(0, 0, 0, (void)0, STAGE_B(1, t1, 0));
    PHASE(0, 0, 1, (void)0, STAGE_B(1, t1, 1));
    PHASE(0, 1, 0, (void)0, (void)0);
    PHASE(0, 1, 1, WAITQ,   if (!last) STAGE_A(0, t2));
    // phases 5-8: consume buf1 (tile 2i+1); stage B(t2)->buf0, A(t3)->buf1 (ph8: A last read ph7)
    PHASE(1, 0, 0, (void)0, if (!last) STAGE_B(0, t2, 0));
    PHASE(1, 0, 1, (void)0, if (!last) STAGE_B(0, t2, 1));
    PHASE(1, 1, 0, (void)0, (void)0);
    PHASE(1, 1, 1, WAITQ,   if (!last) STAGE_A(1, t3));
  }
#undef WAITQ
#undef PHASE
#undef STAGE_A
#undef STAGE_B

  if (EPI == 0) {
    int which = n0 >> 10;   // uniform per block (256-tile never crosses a 1024 boundary)
    if (which < 2) {
      #pragma unroll
      for (int mf=0; mf<4; ++mf) {
        #pragma unroll
        for (int nf=0; nf<4; ++nf) {
          int n = n0 + wc*64 + nf*16 + lr;
          int hd = n & 1023, h2 = hd >> 6, d = hd & 63;
          #pragma unroll
          for (int r=0;r<4;r++) {
            int m = m0 + wr*64 + mf*16 + lg*4 + r;
            int b = m >> 11, s = m & 2047;
            size_t bh = (size_t)(b*HH + h2);
            if (which == 0) Qp[(bh*SS + s)*DD + d] = (bf16_t)(acc[mf][nf][r] * QSCALE);
            else            Kp[(bh*SS + s)*DD + d] = (bf16_t)acc[mf][nf][r];
          }
        }
      }
    } else {
      // V^T: thread holds 4 consecutive s-values -> one 8B bf16x4 store
      #pragma unroll
      for (int mf=0; mf<4; ++mf) {
        #pragma unroll
        for (int nf=0; nf<4; ++nf) {
          int n = n0 + wc*64 + nf*16 + lr;
          int hd = n & 1023, h2 = hd >> 6, d = hd & 63;
          int m = m0 + wr*64 + mf*16 + lg*4;      // s base, multiple of 4
          int b = m >> 11, s = m & 2047;
          size_t bh = (size_t)(b*HH + h2);
          bf16x4 vv;
          vv[0] = (bf16_t)acc[mf][nf][0];
          vv[1] = (bf16_t)acc[mf][nf][1];
          vv[2] = (bf16_t)acc[mf][nf][2];
          vv[3] = (bf16_t)acc[mf][nf][3];
          *reinterpret_cast<bf16x4*>(Vtp + (bh*DD + d)*SS + s) = vv;
        }
      }
    }
  } else {
    float bv[4];
    #pragma unroll
    for (int nf=0;nf<4;nf++) bv[nf] = bias[n0 + wc*64 + nf*16 + lr];
    #pragma unroll
    for (int mf=0; mf<4; ++mf)
      #pragma unroll
      for (int nf=0; nf<4; ++nf) {
        int n = n0 + wc*64 + nf*16 + lr;
        #pragma unroll
        for (int r=0;r<4;r++) {
          int m = m0 + wr*64 + mf*16 + lg*4 + r;
          Cout[(size_t)m*HD + n] = acc[mf][nf][r] + bv[nf];
        }
      }
  }
}

// ---------- flash attention (causal), v4: swapped QK^T, in-register P ----------
__global__ __launch_bounds__(512)
void k_attn(const bf16_t* __restrict__ Q, const bf16_t* __restrict__ K,
            const bf16_t* __restrict__ Vt, bf16_t* __restrict__ AO) {
  __shared__ __align__(16) bf16_t Ks[2][64*64];
  __shared__ __align__(16) bf16_t Vs[2][64*64];

  int id = blockIdx.x;
  int m8 = id & 7, d8 = id >> 3;
  int bh = m8*8 + (d8 >> 3);
  int u  = d8 & 7;

  int tid = threadIdx.x, lane = tid & 63, w = tid >> 6;
  int lr = lane & 15, lg = lane >> 4;
  const bf16_t* Qb = Q  + (size_t)bh * SS * DD;
  const bf16_t* Kp = K  + (size_t)bh * SS * DD;
  const bf16_t* Vp = Vt + (size_t)bh * DD * SS;
  int b = bh >> 4, h = bh & 15;

  int srow = tid >> 3;
  int gchunk = (tid & 7) ^ (srow & 7);

#define STAGE_KV(t, buf) do { \
    int kv0_ = (t)*64; \
    gload_lds16(Kp + (size_t)(kv0_ + srow)*DD + gchunk*8, (char*)Ks[buf] + w*1024); \
    gload_lds16(Vp + (size_t)srow*SS + kv0_ + gchunk*8,   (char*)Vs[buf] + w*1024); \
  } while(0)

  for (int ph = 0; ph < 2; ++ph) {
    int p = ph ? (15 - u) : u;
    int nt = 2*p + 2;
    int qrow0 = p*128 + w*16;
    int q = qrow0 + lr;               // this lane's q row

    bf16x8 qf[2];
    #pragma unroll
    for (int kk=0;kk<2;kk++)
      qf[kk] = *reinterpret_cast<const bf16x8*>(Qb + (size_t)(qrow0 + lr)*DD + kk*32 + lg*8);

    f32x4 po[4];                      // O^T: po[ctd][r] = O[q][d=ctd*16+lg*4+r]
    #pragma unroll
    for (int i=0;i<4;i++) po[i] = (f32x4){0.f,0.f,0.f,0.f};
    float accl = 0.f;
    float mrun = NEG_INF;

    STAGE_KV(0, 0);
    for (int t = 0; t < nt; ++t) {
      __syncthreads();
      if (t+1 < nt) STAGE_KV(t+1, (t+1)&1);
      const bf16_t* Kb = Ks[t&1];
      const bf16_t* Vb = Vs[t&1];
      int kv0 = t*64;
      if (kv0 > qrow0 + 15) continue;

      // ---- S^T = K Q^T : sa[ct][r] = S[q][kv0+ct*16+lg*4+r] ----
      f32x4 sa[4];
      #pragma unroll
      for (int ct=0; ct<4; ++ct) {
        int rr = ct*16 + lr;
        int sw = rr & 7;
        bf16x8 k0 = *reinterpret_cast<const bf16x8*>(Kb + rr*64 + ((lg     ^ sw) << 3));
        bf16x8 k1 = *reinterpret_cast<const bf16x8*>(Kb + rr*64 + (((4+lg) ^ sw) << 3));
        f32x4 c = (f32x4){0.f,0.f,0.f,0.f};
        c = MFMA16(k0, qf[0], c);
        c = MFMA16(k1, qf[1], c);
        sa[ct] = c;
      }
      if (kv0 + 63 > qrow0) {          // tile crosses diagonal for this wave
        #pragma unroll
        for (int ct=0;ct<4;ct++) {
          #pragma unroll
          for (int r=0;r<4;r++) {
            int kv = kv0 + ct*16 + lg*4 + r;
            if (kv > q) sa[ct][r] = NEG_INF;
          }
        }
      }
      // ---- column max: 15 local fmax + 2 shfl ----
      float v01 = fmaxf(fmaxf(sa[0][0],sa[0][1]), fmaxf(sa[0][2],sa[0][3]));
      float v23 = fmaxf(fmaxf(sa[1][0],sa[1][1]), fmaxf(sa[1][2],sa[1][3]));
      float v45 = fmaxf(fmaxf(sa[2][0],sa[2][1]), fmaxf(sa[2][2],sa[2][3]));
      float v67 = fmaxf(fmaxf(sa[3][0],sa[3][1]), fmaxf(sa[3][2],sa[3][3]));
      float vm = fmaxf(fmaxf(v01,v23), fmaxf(v45,v67));
      vm = fmaxf(vm, __shfl_xor(vm, 16));
      vm = fmaxf(vm, __shfl_xor(vm, 32));
      // ---- defer-max: rescale only on wave-wide growth > 8 (log2) ----
      if (!__all(vm - mrun <= 8.0f)) {
        float mn = fmaxf(mrun, vm);
        float fs = __builtin_amdgcn_exp2f(mrun - mn);
        mrun = mn;
        accl *= fs;
        #pragma unroll
        for (int i=0;i<4;i++) po[i] *= fs;
      }
      // ---- P = exp2(S - m): pack PV B-frags in registers; local row-sum ----
      bf16x8 pf[2];
      float rs = 0.f;
      #pragma unroll
      for (int ct=0;ct<4;ct++) {
        #pragma unroll
        for (int r=0;r<4;r++) {
          float pv = __builtin_amdgcn_exp2f(sa[ct][r] - mrun);
          rs += pv;
          pf[ct>>1][(ct&1)*4 + r] = (bf16_t)pv;
        }
      }
      rs += __shfl_xor(rs, 16);
      rs += __shfl_xor(rs, 32);
      accl += rs;
      // ---- O^T += V^T-frag x P^T-frag ----
      #pragma unroll
      for (int ctd=0; ctd<4; ++ctd) {
        int rr = ctd*16 + lr;
        int sw8 = rr & 7;
        int sub = (lg & 1) << 3;
        const char* rowb = (const char*)Vb + rr*128;
        #pragma unroll
        for (int kk=0; kk<2; ++kk) {
          int c0 = kk*4 + (lg>>1);
          bf16x4 lo = *reinterpret_cast<const bf16x4*>(rowb + (((c0     ^ sw8) << 4) | sub));
          bf16x4 hi = *reinterpret_cast<const bf16x4*>(rowb + ((((c0+2) ^ sw8) << 4) | sub));
          bf16x8 vf;
          vf[0]=lo[0]; vf[1]=lo[1]; vf[2]=lo[2]; vf[3]=lo[3];
          vf[4]=hi[0]; vf[5]=hi[1]; vf[6]=hi[2]; vf[7]=hi[3];
          po[ctd] = MFMA16(vf, pf[kk], po[ctd]);
        }
      }
    }
    // ---- epilogue: O /= l; lane owns q row -> 4x bf16x4 stores ----
    {
      float inv = 1.0f / accl;
      bf16_t* dst = AO + (size_t)(b*SS + q)*HD + h*DD;
      #pragma unroll
      for (int ctd=0;ctd<4;ctd++) {
        bf16x4 vv;
        #pragma unroll
        for (int r=0;r<4;r++) vv[r] = (bf16_t)(po[ctd][r] * inv);
        *reinterpret_cast<bf16x4*>(dst + ctd*16 + lg*4) = vv;
      }
    }
  }
#undef STAGE_KV
}

extern "C" void kernel_launch(void* const* d_in, const int* in_sizes, int n_in,
                              void* d_out, int out_size, void* d_ws, size_t ws_size,
                              hipStream_t stream) {
  const float* x  = (const float*)d_in[0];
  const float* Wq = (const float*)d_in[1];
  const float* Wk = (const float*)d_in[2];
  const float* Wv = (const float*)d_in[3];
  const float* Wo = (const float*)d_in[4];
  const float* bo = (const float*)d_in[5];
  float* out = (float*)d_out;

  char* ws = (char*)d_ws;
  bf16_t* xb  = (bf16_t*)(ws + 0);          // [8192,1024]        16 MB
  bf16_t* wt  = (bf16_t*)(ws + 16777216);   // [3072,1024]         6 MB
  bf16_t* wob = (bf16_t*)(ws + 23068672);   // [1024,1024]         2 MB
  bf16_t* Qb  = (bf16_t*)(ws + 25165824);   // [B,H,S,D]          16 MB
  bf16_t* Kb  = (bf16_t*)(ws + 41943040);   // [B,H,S,D]          16 MB
  bf16_t* Vtb = (bf16_t*)(ws + 58720256);   // [B,H,D,S]          16 MB
  bf16_t* AO  = (bf16_t*)(ws + 75497472);   // [8192,1024]        16 MB

  k_f32_to_bf16<<<(MM*EE/8)/256, 256, 0, stream>>>(x,  xb,  MM*EE/8);
  k_f32_to_bf16<<<(EE*EE/8)/256, 256, 0, stream>>>(Wo, wob, EE*EE/8);
  dim3 gw(48, 16);
  k_conv_wqkv<<<gw, 256, 0, stream>>>(Wq, Wk, Wv, wt);

  // QKV: 64 m-tiles x 12 n-tiles = 768 blocks = exactly 3 rounds
  k_gemm8<0,12><<<768, 512, 0, stream>>>(xb, wt, Qb, Kb, Vtb, nullptr, nullptr);

  k_attn<<<BB*HH*8, 512, 0, stream>>>(Qb, Kb, Vtb, AO);

  // proj: 64 m-tiles x 4 n-tiles = 256 blocks = exactly 1 round
  k_gemm8<1,4><<<256, 512, 0, stream>>>(AO, wob, nullptr, nullptr, nullptr, bo, out);
}